// Round 5
// baseline (686.338 us; speedup 1.0000x reference)
//
#include <hip/hip_runtime.h>
#include <hip/hip_bf16.h>

// Established facts (R3-R19): d_in = setup_inputs() dict order; floats fp32;
// edges int32; output fp32 [20000,128]. Best = R15 612us (pull 83us/layer).
// Pull invariants: -40% VALU -> flat (R17); +occ via 2-wave blocks -> flat
// (R18); head-split -> WORSE, FETCH ~= NXCD x footprint (R19: per-XCD L2s
// each fill their own copy; footprint shrink can't help). R17's edge_w:
// per-lane divergent gathers hit 5.8 TB/s line traffic vs pull's 2.9 TB/s
// -> pull is MLP-bound: coalesced row-gather = 4 lines in flight/instr,
// divergent = 64. This round: node-per-lane pull (wave = 32 nodes x 2
// heads, acc in 64 VGPRs, per-lane gathers), bit-identical accumulation
// order; semantic MLP via proven standalone semw_nodes.
#define NN 20000
#define RR 3
#define EE 320000
#define FD 128
#define AH 32
#define NP1 (NN + 1)
#define NEG_SLOPE 0.2f
#define NPW 32  // nodes per wave in pull_nl

__device__ __forceinline__ int clamp_idx(int v) {
  v = v < 0 ? 0 : v;
  return v < NN ? v : NN - 1;
}
// leaky_relu(e) == max(e, 0.2*e) for all e (0.2e > e when e < 0)
__device__ __forceinline__ float leaky_exp(float e) {
  return __expf(fmaxf(e, NEG_SLOPE * e));
}
__device__ __forceinline__ float bf2f(unsigned short u) {
  union { unsigned int i; float f; } c;
  c.i = ((unsigned int)u) << 16;
  return c.f;
}
// fp32 -> bf16 with round-to-nearest-even (values are finite, |v| ~ O(1))
__device__ __forceinline__ unsigned short f2bf(float v) {
  union { float f; unsigned int i; } c;
  c.f = v;
  const unsigned int u = c.i;
  return (unsigned short)((u + 0x7fffu + ((u >> 16) & 1u)) >> 16);
}

// ----------------------------- CSR build -----------------------------------
__global__ void csr_count(const int* __restrict__ edg, int* __restrict__ cnt) {
  const int idx = blockIdx.x * blockDim.x + threadIdx.x;
  if (idx >= RR * EE) return;
  const int r = idx / EE, k = idx - r * EE;
  const int dst = clamp_idx(edg[(size_t)r * 2 * EE + EE + k]);
  atomicAdd(&cnt[r * NN + dst], 1);
}

// parallel Hillis-Steele scan over 256 partials (proven R19)
__global__ void csr_scan(const int* __restrict__ cnt, int* __restrict__ starts,
                         int* __restrict__ cursor) {
  __shared__ int part[256];
  const int r = blockIdx.x, t = threadIdx.x;
  const int CH = (NN + 255) / 256;  // 79
  const int lo = t * CH, hi = min(lo + CH, NN);
  int s = 0;
  for (int i = lo; i < hi; ++i) s += cnt[r * NN + i];
  part[t] = s;
  __syncthreads();
  for (int off = 1; off < 256; off <<= 1) {
    const int x = part[t];
    const int y = (t >= off) ? part[t - off] : 0;
    __syncthreads();
    part[t] = x + y;
    __syncthreads();
  }
  int run = (t == 0) ? 0 : part[t - 1];
  for (int i = lo; i < hi; ++i) {
    starts[r * NP1 + i] = run;
    cursor[r * NP1 + i] = run;
    run += cnt[r * NN + i];
  }
  if (t == 255) starts[r * NP1 + NN] = run;
}

__global__ void csr_scatter(const int* __restrict__ edg, int* __restrict__ cursor,
                            int* __restrict__ csrsrc) {
  const int idx = blockIdx.x * blockDim.x + threadIdx.x;
  if (idx >= RR * EE) return;
  const int r = idx / EE, k = idx - r * EE;
  const int src = clamp_idx(edg[(size_t)r * 2 * EE + k]);
  const int dst = clamp_idx(edg[(size_t)r * 2 * EE + EE + k]);
  const int pos = atomicAdd(&cursor[r * NP1 + dst], 1);
  csrsrc[(size_t)r * EE + pos] = src;
}

// ---------------------------------------------------------------------------
// Merged gemm (proven): block = 1 wave, BN=16 nodes, thread j owns cols j
// (head 0) and j+64 (head 1). el/er via shfl. f stored bf16.
// ---------------------------------------------------------------------------
#define BN 16
__global__ void __launch_bounds__(64, 4) gemm_all(
    const float* __restrict__ hin,            // [N,128]
    const float* __restrict__ W,              // [3,128,128]
    const float* __restrict__ al,             // [3,128]
    const float* __restrict__ ar,             // [3,128]
    unsigned short* __restrict__ fb,          // [3,N,128] bf16
    float* __restrict__ el,                   // [3,N,2]
    float* __restrict__ er) {
  __shared__ float lh[BN * FD];  // 8 KB
  const int blocksPerRel = NN / BN;  // 1250
  const int r = blockIdx.x / blocksPerRel;
  const int n0 = (blockIdx.x % blocksPerRel) * BN;
  const int j = threadIdx.x;  // 0..63

  {
    const float4* s4 = (const float4*)&hin[(size_t)n0 * FD];
    float4* d4 = (float4*)lh;
#pragma unroll
    for (int t = 0; t < 8; ++t) d4[j + 64 * t] = s4[j + 64 * t];
  }
  __syncthreads();

  const float* Wr = W + (size_t)r * FD * FD;
  float acc0[BN], acc1[BN];
#pragma unroll
  for (int i = 0; i < BN; ++i) { acc0[i] = 0.f; acc1[i] = 0.f; }

  for (int k4 = 0; k4 < FD; k4 += 4) {
    const float wa0 = Wr[(size_t)(k4 + 0) * FD + j];
    const float wb0 = Wr[(size_t)(k4 + 0) * FD + j + 64];
    const float wa1 = Wr[(size_t)(k4 + 1) * FD + j];
    const float wb1 = Wr[(size_t)(k4 + 1) * FD + j + 64];
    const float wa2 = Wr[(size_t)(k4 + 2) * FD + j];
    const float wb2 = Wr[(size_t)(k4 + 2) * FD + j + 64];
    const float wa3 = Wr[(size_t)(k4 + 3) * FD + j];
    const float wb3 = Wr[(size_t)(k4 + 3) * FD + j + 64];
#pragma unroll
    for (int i = 0; i < BN; ++i) {
      const float4 h4 = *(const float4*)&lh[i * FD + k4];
      acc0[i] = fmaf(h4.x, wa0, fmaf(h4.y, wa1, fmaf(h4.z, wa2, fmaf(h4.w, wa3, acc0[i]))));
      acc1[i] = fmaf(h4.x, wb0, fmaf(h4.y, wb1, fmaf(h4.z, wb2, fmaf(h4.w, wb3, acc1[i]))));
    }
  }

  const float al0 = al[r * FD + j];
  const float al1v = al[r * FD + j + 64];
  const float ar0 = ar[r * FD + j];
  const float ar1v = ar[r * FD + j + 64];

#pragma unroll
  for (int i = 0; i < BN; ++i) {
    const size_t row = ((size_t)r * NN + n0 + i) * FD;
    fb[row + j] = f2bf(acc0[i]);
    fb[row + j + 64] = f2bf(acc1[i]);
    float e0 = acc0[i] * al0;
    float e1 = acc1[i] * al1v;
    float u0 = acc0[i] * ar0;
    float u1 = acc1[i] * ar1v;
#pragma unroll
    for (int off = 32; off > 0; off >>= 1) {
      e0 += __shfl_down(e0, off, 64);
      e1 += __shfl_down(e1, off, 64);
      u0 += __shfl_down(u0, off, 64);
      u1 += __shfl_down(u1, off, 64);
    }
    if (j == 0) {
      const size_t base = ((size_t)r * NN + n0 + i) * 2;
      el[base + 0] = e0;
      el[base + 1] = e1;
      er[base + 0] = u0;
      er[base + 1] = u1;
    }
  }
}

// ---------------------------------------------------------------------------
// Node-per-lane pull: wave = 32 nodes x 2 heads; lane l owns node n0+(l&31),
// head l>>5, with a 64-VGPR accumulator (32 x float2 = 64 cols). Per edge
// round, all 64 lanes gather from DIFFERENT fb rows -> 64 independent cache
// lines in flight per vmem instruction (R17's edge_w showed this pattern
// sustains ~2x the line throughput of wave-coalesced row gathers). A lane's
// 32 column loads span 2 lines -> L1 hits after the first two. Accumulation
// is k-ascending in CSR order per column => bit-identical to R15.
// ---------------------------------------------------------------------------
__global__ void __launch_bounds__(64, 2) pull_nl(
    const int* __restrict__ starts,   // [3,NP1]
    const int* __restrict__ csrsrc,   // [3,E]
    const float* __restrict__ el,     // [3,N,2]
    const float* __restrict__ er,
    const unsigned short* __restrict__ fb,  // [3,N,128] bf16
    const float* __restrict__ b,      // [3,128]
    int do_relu,
    float* __restrict__ z) {          // [3,N,128]
  const int bpr = NN / NPW;               // 625
  const int r = blockIdx.x / bpr;
  const int n0 = (blockIdx.x - r * bpr) * NPW;
  const int l = threadIdx.x;              // 0..63
  const int h = l >> 5;                   // head
  const int n = n0 + (l & 31);
  const int rn = r * NN + n;
  const int* st = starts + r * NP1;
  const int* cs = csrsrc + (size_t)r * EE;
  const float2* el2 = (const float2*)(el + (size_t)r * NN * 2);
  const unsigned int* fru = (const unsigned int*)(fb + (size_t)r * NN * FD);
  const int s0 = st[n];
  const int deg = st[n + 1] - s0;
  const float ern = er[(size_t)rn * 2 + h];

  float2 acc[32];
#pragma unroll
  for (int i = 0; i < 32; ++i) acc[i] = make_float2(0.f, 0.f);
  float den = 0.f;

  int md = deg;
#pragma unroll
  for (int off = 32; off > 0; off >>= 1) md = max(md, __shfl_xor(md, off, 64));

  for (int k = 0; k < md; ++k) {
    if (k < deg) {
      const int src = cs[s0 + k];
      const float2 e2 = el2[src];
      const float w = leaky_exp((h ? e2.y : e2.x) + ern);
      den += w;
      const unsigned int* frow = fru + (src << 6) + (h << 5);
#pragma unroll
      for (int cp = 0; cp < 32; ++cp) {
        const unsigned int fv = frow[cp];
        acc[cp].x += w * bf2f((unsigned short)(fv & 0xffff));
        acc[cp].y += w * bf2f((unsigned short)(fv >> 16));
      }
    }
  }

  const float inv = 1.f / fmaxf(den, 1e-9f);
  const float* bb = b + r * FD + h * 64;
  float* zr = z + (size_t)rn * FD + h * 64;
#pragma unroll
  for (int cp = 0; cp < 32; ++cp) {
    float vx = acc[cp].x * inv + bb[2 * cp];
    float vy = acc[cp].y * inv + bb[2 * cp + 1];
    if (do_relu) { vx = fmaxf(vx, 0.f); vy = fmaxf(vy, 0.f); }
    ((float2*)zr)[cp] = make_float2(vx, vy);
  }
}

// semantic-attention logits per (node, relation) — proven (R10 path)
__global__ void semw_nodes(const float* __restrict__ z,
                           const float* __restrict__ aw1,
                           const float* __restrict__ ab1,
                           const float* __restrict__ aw2,
                           float* __restrict__ wv) {
  __shared__ float lz[2][FD];
  __shared__ float red[2][4][AH];
  __shared__ float wcol[2][AH];
  const int g = threadIdx.x >> 7;
  const int t = threadIdx.x & 127;
  const int pair = blockIdx.x * 2 + g;
  const int n = pair / RR;
  const int r = pair - n * RR;
  lz[g][t] = z[((size_t)r * NN + n) * FD + t];
  __syncthreads();
  const int col = t & 31;
  const int part = t >> 5;
  float acc = 0.f;
#pragma unroll
  for (int kk = 0; kk < 32; ++kk) {
    const int k = part * 32 + kk;
    acc += lz[g][k] * aw1[(size_t)k * AH + col];
  }
  red[g][part][col] = acc;
  __syncthreads();
  if (part == 0) {
    float s = red[g][0][col] + red[g][1][col] + red[g][2][col] + red[g][3][col];
    wcol[g][col] = tanhf(s + ab1[col]) * aw2[col];
  }
  __syncthreads();
  if (t == 0) {
    float w = 0.f;
#pragma unroll
    for (int c = 0; c < AH; ++c) w += wcol[g][c];
    wv[(size_t)r * NN + n] = w;
  }
}

// Fused reduce + beta (proven)
__global__ void reduce_beta(const float* __restrict__ wv, float* __restrict__ S) {
  __shared__ float p[256];
  const int t = threadIdx.x;
  float tot[RR];
  for (int r = 0; r < RR; ++r) {
    float s = 0.f;
    for (int n = t; n < NN; n += 256) s += wv[(size_t)r * NN + n];
    p[t] = s;
    __syncthreads();
    for (int off = 128; off > 0; off >>= 1) {
      if (t < off) p[t] += p[t + off];
      __syncthreads();
    }
    tot[r] = p[0];
    __syncthreads();
  }
  if (t == 0) {
    S[0] = tot[0]; S[1] = tot[1]; S[2] = tot[2];
    float w0 = tot[0] / (float)NN, w1 = tot[1] / (float)NN, w2 = tot[2] / (float)NN;
    float mx = fmaxf(w0, fmaxf(w1, w2));
    float e0 = __expf(w0 - mx), e1 = __expf(w1 - mx), e2 = __expf(w2 - mx);
    float inv = 1.f / (e0 + e1 + e2);
    S[4] = e0 * inv; S[5] = e1 * inv; S[6] = e2 * inv;
  }
}

__global__ void combine_f32(const float* __restrict__ z,
                            const float* __restrict__ S,
                            float* __restrict__ out) {
  const int idx = blockIdx.x * blockDim.x + threadIdx.x;
  if (idx >= NN * FD) return;
  out[idx] = S[4] * z[idx] + S[5] * z[(size_t)NN * FD + idx] +
             S[6] * z[2 * (size_t)NN * FD + idx];
}

// ------------------- fallback kernels (R10 CSR path, proven) ----------------
__global__ void gemm_el_er(const float* __restrict__ hin,
                           const float* __restrict__ W,
                           const float* __restrict__ al,
                           const float* __restrict__ ar,
                           float* __restrict__ f,
                           float* __restrict__ el,
                           float* __restrict__ er) {
  const int B8 = 8;
  __shared__ float lh[B8 * FD];
  const int j = threadIdx.x;
  const int n0 = blockIdx.x * B8;
#pragma unroll
  for (int i = 0; i < B8; ++i)
    lh[i * FD + j] = hin[(size_t)(n0 + i) * FD + j];
  __syncthreads();
  float acc[B8];
#pragma unroll
  for (int i = 0; i < B8; ++i) acc[i] = 0.f;
  for (int k = 0; k < FD; ++k) {
    const float w = W[(size_t)k * FD + j];
#pragma unroll
    for (int i = 0; i < B8; ++i) acc[i] += lh[i * FD + k] * w;
  }
  const float alv = al[j];
  const float arv = ar[j];
#pragma unroll
  for (int i = 0; i < B8; ++i) f[(size_t)(n0 + i) * FD + j] = acc[i];
  __syncthreads();
#pragma unroll
  for (int i = 0; i < B8; ++i) lh[i * FD + j] = acc[i] * alv;
  __syncthreads();
  if (j < B8 * 2) {
    const int i = j >> 1, h = j & 1;
    const float* p = &lh[i * FD + h * 64];
    float s = 0.f;
    for (int d = 0; d < 64; ++d) s += p[d];
    el[(size_t)(n0 + i) * 2 + h] = s;
  }
  __syncthreads();
#pragma unroll
  for (int i = 0; i < B8; ++i) lh[i * FD + j] = acc[i] * arv;
  __syncthreads();
  if (j < B8 * 2) {
    const int i = j >> 1, h = j & 1;
    const float* p = &lh[i * FD + h * 64];
    float s = 0.f;
    for (int d = 0; d < 64; ++d) s += p[d];
    er[(size_t)(n0 + i) * 2 + h] = s;
  }
}

__global__ void pull_aggr(const int* __restrict__ starts,
                          const int* __restrict__ csrsrc,
                          const float* __restrict__ el,
                          const float* __restrict__ er,
                          const float* __restrict__ f,
                          const float* __restrict__ b,
                          int do_relu,
                          float* __restrict__ z) {
  const int n = blockIdx.x;
  const int j = threadIdx.x;
  const int h = j >> 6;
  const int s0 = starts[n], s1 = starts[n + 1];
  const float ern = er[(size_t)n * 2 + h];
  float acc = 0.f, den = 0.f;
  for (int p = s0; p < s1; ++p) {
    const int src = csrsrc[p];
    const float w = leaky_exp(el[(size_t)src * 2 + h] + ern);
    den += w;
    acc += w * f[(size_t)src * FD + j];
  }
  float v = acc / fmaxf(den, 1e-9f) + b[j];
  if (do_relu) v = fmaxf(v, 0.f);
  z[(size_t)n * FD + j] = v;
}

// ---------------------------------------------------------------------------
extern "C" void kernel_launch(void* const* d_in, const int* in_sizes, int n_in,
                              void* d_out, int out_size, void* d_ws, size_t ws_size,
                              hipStream_t stream) {
  const float* x   = (const float*)d_in[0];
  const int*   edg = (const int*)d_in[1];
  const float* W1  = (const float*)d_in[2];
  const float* al1 = (const float*)d_in[3];
  const float* ar1 = (const float*)d_in[4];
  const float* b1  = (const float*)d_in[5];
  const float* W2  = (const float*)d_in[6];
  const float* al2 = (const float*)d_in[7];
  const float* ar2 = (const float*)d_in[8];
  const float* b2  = (const float*)d_in[9];
  const float* aw1 = (const float*)d_in[10];
  const float* ab1 = (const float*)d_in[11];
  const float* aw2 = (const float*)d_in[12];
  const float* bw1 = (const float*)d_in[13];
  const float* bb1 = (const float*)d_in[14];
  const float* bw2 = (const float*)d_in[15];
  float* out = (float*)d_out;

  const size_t need_big = 67200128;  // gate proven on this ws
  if (ws_size >= need_big) {
    float* S      = (float*)d_ws;                    // 16
    float* wv     = S + 16;                          // RR*NN
    float* el     = wv + (size_t)RR * NN;            // RR*NN*2
    float* er     = el + (size_t)RR * NN * 2;        // RR*NN*2
    float* z      = er + (size_t)RR * NN * 2;        // RR*NN*FD fp32
    unsigned short* fb = (unsigned short*)(z + (size_t)RR * NN * FD);  // bf16
    int*   cnt    = (int*)(fb + (size_t)RR * NN * FD);  // RR*NN
    int*   starts = cnt + RR * NN;                   // RR*NP1
    int*   cursor = starts + RR * NP1;               // RR*NP1
    int*   csrsrc = cursor + RR * NP1;               // RR*EE

    hipMemsetAsync(cnt, 0, (size_t)RR * NN * sizeof(int), stream);
    csr_count<<<(RR * EE + 255) / 256, 256, 0, stream>>>(edg, cnt);
    csr_scan<<<RR, 256, 0, stream>>>(cnt, starts, cursor);
    csr_scatter<<<(RR * EE + 255) / 256, 256, 0, stream>>>(edg, cursor, csrsrc);

    // layer 1
    gemm_all<<<RR * (NN / BN), 64, 0, stream>>>(x, W1, al1, ar1, fb, el, er);
    pull_nl<<<RR * (NN / NPW), 64, 0, stream>>>(starts, csrsrc, el, er, fb,
                                                b1, 1, z);
    semw_nodes<<<NN * RR / 2, 256, 0, stream>>>(z, aw1, ab1, aw2, wv);
    reduce_beta<<<1, 256, 0, stream>>>(wv, S);
    combine_f32<<<(NN * FD + 255) / 256, 256, 0, stream>>>(z, S, out);  // hmid

    // layer 2
    gemm_all<<<RR * (NN / BN), 64, 0, stream>>>(out, W2, al2, ar2, fb, el, er);
    pull_nl<<<RR * (NN / NPW), 64, 0, stream>>>(starts, csrsrc, el, er, fb,
                                                b2, 0, z);
    semw_nodes<<<NN * RR / 2, 256, 0, stream>>>(z, bw1, bb1, bw2, wv);
    reduce_beta<<<1, 256, 0, stream>>>(wv, S);
    combine_f32<<<(NN * FD + 255) / 256, 256, 0, stream>>>(z, S, out);
    return;
  }

  // ---------------- fallback: R10 CSR path (46 MB, proven) ----------------
  float* S      = (float*)d_ws;
  float* wv     = S + 16;
  float* el     = wv + (size_t)RR * NN;
  float* er     = el + (size_t)NN * 2;
  float* f      = er + (size_t)NN * 2;
  float* z      = f + (size_t)NN * FD;
  int*   cnt    = (int*)(z + (size_t)RR * NN * FD);
  int*   starts = cnt + RR * NN;
  int*   cursor = starts + RR * NP1;
  int*   csrsrc = cursor + RR * NP1;

  hipMemsetAsync(cnt, 0, (size_t)RR * NN * sizeof(int), stream);
  csr_count<<<(RR * EE + 255) / 256, 256, 0, stream>>>(edg, cnt);
  csr_scan<<<RR, 256, 0, stream>>>(cnt, starts, cursor);
  csr_scatter<<<(RR * EE + 255) / 256, 256, 0, stream>>>(edg, cursor, csrsrc);

  for (int r = 0; r < RR; ++r) {
    gemm_el_er<<<NN / 8, 128, 0, stream>>>(
        x, W1 + (size_t)r * FD * FD, al1 + r * FD, ar1 + r * FD, f, el, er);
    pull_aggr<<<NN, 128, 0, stream>>>(starts + r * NP1, csrsrc + (size_t)r * EE,
                                      el, er, f, b1 + r * FD, 1,
                                      z + (size_t)r * NN * FD);
  }
  semw_nodes<<<NN * RR / 2, 256, 0, stream>>>(z, aw1, ab1, aw2, wv);
  reduce_beta<<<1, 256, 0, stream>>>(wv, S);
  combine_f32<<<(NN * FD + 255) / 256, 256, 0, stream>>>(z, S, out);

  for (int r = 0; r < RR; ++r) {
    gemm_el_er<<<NN / 8, 128, 0, stream>>>(
        out, W2 + (size_t)r * FD * FD, al2 + r * FD, ar2 + r * FD, f, el, er);
    pull_aggr<<<NN, 128, 0, stream>>>(starts + r * NP1, csrsrc + (size_t)r * EE,
                                      el, er, f, b2 + r * FD, 0,
                                      z + (size_t)r * NN * FD);
  }
  semw_nodes<<<NN * RR / 2, 256, 0, stream>>>(z, bw1, bb1, bw2, wv);
  reduce_beta<<<1, 256, 0, stream>>>(wv, S);
  combine_f32<<<(NN * FD + 255) / 256, 256, 0, stream>>>(z, S, out);
}

// Round 6
// 631.714 us; speedup vs baseline: 1.0865x; 1.0865x over previous
//
#include <hip/hip_runtime.h>
#include <hip/hip_bf16.h>

// Established facts (R3-R20): d_in = setup_inputs() dict order; floats fp32;
// edges int32; output fp32 [20000,128]. Best = R15 612us. Pull history:
// coalesced row-gather = 1.5 TB/s eff (R15, invariant to VALU/occ tweaks);
// head-split FETCH ~= NXCD x footprint (R19, per-XCD L2 duplication);
// node-per-lane divergent gather = 2.5 TB/s, 75us, but occ 15.5% (R20:
// only 1875 one-wave blocks; VALU 12% -> latency-bound, waves starved).
// This round: (a) split (node,head) across 4 quad-lanes -> wave = 8 nodes x
// 2 heads x 4 quads, block = 4 waves = 32 nodes -> 7500 waves (~29/CU);
// acc = 16 VGPR; lb(256,4) caps VGPR at 128 (no R16 spill). (b) semantic
// MLP fused back at block scope via 16KB LDS (deletes semw_nodes).
// z math bit-identical (k-ascending per column, same weights).
#define NN 20000
#define RR 3
#define EE 320000
#define FD 128
#define AH 32
#define NP1 (NN + 1)
#define NEG_SLOPE 0.2f
#define NW 4            // waves per block in pull_fused
#define NPW2 8          // nodes per wave
#define NPB (NW * NPW2) // 32 nodes per block

__device__ __forceinline__ int clamp_idx(int v) {
  v = v < 0 ? 0 : v;
  return v < NN ? v : NN - 1;
}
// leaky_relu(e) == max(e, 0.2*e) for all e (0.2e > e when e < 0)
__device__ __forceinline__ float leaky_exp(float e) {
  return __expf(fmaxf(e, NEG_SLOPE * e));
}
__device__ __forceinline__ float bf2f(unsigned short u) {
  union { unsigned int i; float f; } c;
  c.i = ((unsigned int)u) << 16;
  return c.f;
}
// fp32 -> bf16 with round-to-nearest-even (values are finite, |v| ~ O(1))
__device__ __forceinline__ unsigned short f2bf(float v) {
  union { float f; unsigned int i; } c;
  c.f = v;
  const unsigned int u = c.i;
  return (unsigned short)((u + 0x7fffu + ((u >> 16) & 1u)) >> 16);
}

// ----------------------------- CSR build -----------------------------------
__global__ void csr_count(const int* __restrict__ edg, int* __restrict__ cnt) {
  const int idx = blockIdx.x * blockDim.x + threadIdx.x;
  if (idx >= RR * EE) return;
  const int r = idx / EE, k = idx - r * EE;
  const int dst = clamp_idx(edg[(size_t)r * 2 * EE + EE + k]);
  atomicAdd(&cnt[r * NN + dst], 1);
}

// parallel Hillis-Steele scan over 256 partials (proven R19)
__global__ void csr_scan(const int* __restrict__ cnt, int* __restrict__ starts,
                         int* __restrict__ cursor) {
  __shared__ int part[256];
  const int r = blockIdx.x, t = threadIdx.x;
  const int CH = (NN + 255) / 256;  // 79
  const int lo = t * CH, hi = min(lo + CH, NN);
  int s = 0;
  for (int i = lo; i < hi; ++i) s += cnt[r * NN + i];
  part[t] = s;
  __syncthreads();
  for (int off = 1; off < 256; off <<= 1) {
    const int x = part[t];
    const int y = (t >= off) ? part[t - off] : 0;
    __syncthreads();
    part[t] = x + y;
    __syncthreads();
  }
  int run = (t == 0) ? 0 : part[t - 1];
  for (int i = lo; i < hi; ++i) {
    starts[r * NP1 + i] = run;
    cursor[r * NP1 + i] = run;
    run += cnt[r * NN + i];
  }
  if (t == 255) starts[r * NP1 + NN] = run;
}

__global__ void csr_scatter(const int* __restrict__ edg, int* __restrict__ cursor,
                            int* __restrict__ csrsrc) {
  const int idx = blockIdx.x * blockDim.x + threadIdx.x;
  if (idx >= RR * EE) return;
  const int r = idx / EE, k = idx - r * EE;
  const int src = clamp_idx(edg[(size_t)r * 2 * EE + k]);
  const int dst = clamp_idx(edg[(size_t)r * 2 * EE + EE + k]);
  const int pos = atomicAdd(&cursor[r * NP1 + dst], 1);
  csrsrc[(size_t)r * EE + pos] = src;
}

// ---------------------------------------------------------------------------
// Merged gemm (proven): block = 1 wave, BN=16 nodes, thread j owns cols j
// (head 0) and j+64 (head 1). el/er via shfl. f stored bf16.
// ---------------------------------------------------------------------------
#define BN 16
__global__ void __launch_bounds__(64, 4) gemm_all(
    const float* __restrict__ hin,            // [N,128]
    const float* __restrict__ W,              // [3,128,128]
    const float* __restrict__ al,             // [3,128]
    const float* __restrict__ ar,             // [3,128]
    unsigned short* __restrict__ fb,          // [3,N,128] bf16
    float* __restrict__ el,                   // [3,N,2]
    float* __restrict__ er) {
  __shared__ float lh[BN * FD];  // 8 KB
  const int blocksPerRel = NN / BN;  // 1250
  const int r = blockIdx.x / blocksPerRel;
  const int n0 = (blockIdx.x % blocksPerRel) * BN;
  const int j = threadIdx.x;  // 0..63

  {
    const float4* s4 = (const float4*)&hin[(size_t)n0 * FD];
    float4* d4 = (float4*)lh;
#pragma unroll
    for (int t = 0; t < 8; ++t) d4[j + 64 * t] = s4[j + 64 * t];
  }
  __syncthreads();

  const float* Wr = W + (size_t)r * FD * FD;
  float acc0[BN], acc1[BN];
#pragma unroll
  for (int i = 0; i < BN; ++i) { acc0[i] = 0.f; acc1[i] = 0.f; }

  for (int k4 = 0; k4 < FD; k4 += 4) {
    const float wa0 = Wr[(size_t)(k4 + 0) * FD + j];
    const float wb0 = Wr[(size_t)(k4 + 0) * FD + j + 64];
    const float wa1 = Wr[(size_t)(k4 + 1) * FD + j];
    const float wb1 = Wr[(size_t)(k4 + 1) * FD + j + 64];
    const float wa2 = Wr[(size_t)(k4 + 2) * FD + j];
    const float wb2 = Wr[(size_t)(k4 + 2) * FD + j + 64];
    const float wa3 = Wr[(size_t)(k4 + 3) * FD + j];
    const float wb3 = Wr[(size_t)(k4 + 3) * FD + j + 64];
#pragma unroll
    for (int i = 0; i < BN; ++i) {
      const float4 h4 = *(const float4*)&lh[i * FD + k4];
      acc0[i] = fmaf(h4.x, wa0, fmaf(h4.y, wa1, fmaf(h4.z, wa2, fmaf(h4.w, wa3, acc0[i]))));
      acc1[i] = fmaf(h4.x, wb0, fmaf(h4.y, wb1, fmaf(h4.z, wb2, fmaf(h4.w, wb3, acc1[i]))));
    }
  }

  const float al0 = al[r * FD + j];
  const float al1v = al[r * FD + j + 64];
  const float ar0 = ar[r * FD + j];
  const float ar1v = ar[r * FD + j + 64];

#pragma unroll
  for (int i = 0; i < BN; ++i) {
    const size_t row = ((size_t)r * NN + n0 + i) * FD;
    fb[row + j] = f2bf(acc0[i]);
    fb[row + j + 64] = f2bf(acc1[i]);
    float e0 = acc0[i] * al0;
    float e1 = acc1[i] * al1v;
    float u0 = acc0[i] * ar0;
    float u1 = acc1[i] * ar1v;
#pragma unroll
    for (int off = 32; off > 0; off >>= 1) {
      e0 += __shfl_down(e0, off, 64);
      e1 += __shfl_down(e1, off, 64);
      u0 += __shfl_down(u0, off, 64);
      u1 += __shfl_down(u1, off, 64);
    }
    if (j == 0) {
      const size_t base = ((size_t)r * NN + n0 + i) * 2;
      el[base + 0] = e0;
      el[base + 1] = e1;
      er[base + 0] = u0;
      er[base + 1] = u1;
    }
  }
}

// ---------------------------------------------------------------------------
// pull_fused: block = 4 waves = 32 nodes of one relation. Lane l of wave w
// owns (node = nb + w*8 + (l&7), head = (l>>3)&1, quad = l>>4): 8 uint
// gathers (32 B) per edge from fb, per-lane divergent -> max lines in
// flight (proven 2.5 TB/s pattern, now with 4x the waves). acc = 8 x float2
// in VGPRs. Accumulation k-ascending per column => bit-identical z.
// After the edge loop the block stages z in LDS and computes the semantic
// MLP for its 32 nodes (8 threads x 4 cols each + shuffle reduce) -> wv.
// ---------------------------------------------------------------------------
__global__ void __launch_bounds__(256, 4) pull_fused(
    const int* __restrict__ starts,   // [3,NP1]
    const int* __restrict__ csrsrc,   // [3,E]
    const float* __restrict__ el,     // [3,N,2]
    const float* __restrict__ er,
    const unsigned short* __restrict__ fb,  // [3,N,128] bf16
    const float* __restrict__ b,      // [3,128]
    int do_relu,
    const float* __restrict__ aw1,    // [128,32]
    const float* __restrict__ ab1,    // [32]
    const float* __restrict__ aw2,    // [32]
    float* __restrict__ z,            // [3,N,128]
    float* __restrict__ wv) {         // [3,N]
  __shared__ float lz[NPB][FD];  // 16 KB
  const int t = threadIdx.x;
  const int wave = t >> 6;
  const int l = t & 63;
  const int bpr = NN / NPB;  // 625
  const int r = blockIdx.x / bpr;
  const int nb = (blockIdx.x - r * bpr) * NPB;
  const int widx = wave * NPW2 + (l & 7);  // node index within block 0..31
  const int node = nb + widx;
  const int h = (l >> 3) & 1;
  const int q = l >> 4;                    // 0..3
  const int rn = r * NN + node;
  const int* st = starts + r * NP1;
  const int* cs = csrsrc + (size_t)r * EE;
  const float2* el2 = (const float2*)(el + (size_t)r * NN * 2);
  const unsigned int* fru = (const unsigned int*)(fb + (size_t)r * NN * FD);
  const int s0 = st[node];
  const int deg = st[node + 1] - s0;
  const float ern = er[(size_t)rn * 2 + h];

  float2 acc[8];
#pragma unroll
  for (int i = 0; i < 8; ++i) acc[i] = make_float2(0.f, 0.f);
  float den = 0.f;

  // max degree over the 8 nodes of this wave (node id depends only on l&7)
  int md = deg;
  md = max(md, __shfl_xor(md, 1, 64));
  md = max(md, __shfl_xor(md, 2, 64));
  md = max(md, __shfl_xor(md, 4, 64));

  for (int k = 0; k < md; ++k) {
    if (k < deg) {
      const int src = cs[s0 + k];
      const float2 e2 = el2[src];
      const float w = leaky_exp((h ? e2.y : e2.x) + ern);
      den += w;
      const unsigned int* frow = fru + (src << 6) + (h << 5) + (q << 3);
#pragma unroll
      for (int cp = 0; cp < 8; ++cp) {
        const unsigned int fv = frow[cp];
        acc[cp].x += w * bf2f((unsigned short)(fv & 0xffff));
        acc[cp].y += w * bf2f((unsigned short)(fv >> 16));
      }
    }
  }

  const float inv = 1.f / fmaxf(den, 1e-9f);
  const int cbase = h * 64 + q * 16;
  const float* bb = b + r * FD + cbase;
  float* zr = z + (size_t)rn * FD + cbase;
#pragma unroll
  for (int cp = 0; cp < 8; ++cp) {
    float vx = acc[cp].x * inv + bb[2 * cp];
    float vy = acc[cp].y * inv + bb[2 * cp + 1];
    if (do_relu) { vx = fmaxf(vx, 0.f); vy = fmaxf(vy, 0.f); }
    ((float2*)zr)[cp] = make_float2(vx, vy);
    lz[widx][cbase + 2 * cp] = vx;
    lz[widx][cbase + 2 * cp + 1] = vy;
  }
  __syncthreads();

  // ---- fused semantic-attention logit for the block's 32 nodes ----
  // 8 threads per node; thread i handles cols i, i+8, i+16, i+24.
  const int mnode = t >> 3;   // 0..31
  const int i = t & 7;
  float part = 0.f;
#pragma unroll
  for (int cc = 0; cc < 4; ++cc) {
    const int col = i + 8 * cc;
    float a2 = ab1[col];
    for (int k = 0; k < FD; ++k)
      a2 += lz[mnode][k] * aw1[(size_t)k * AH + col];
    part += tanhf(a2) * aw2[col];
  }
  // reduce the 8 partials of each node (lanes mnode*8 .. mnode*8+7)
  part += __shfl_down(part, 4, 64);
  part += __shfl_down(part, 2, 64);
  part += __shfl_down(part, 1, 64);
  if (i == 0) wv[(size_t)r * NN + nb + mnode] = part;
}

// Fused reduce + beta (proven)
__global__ void reduce_beta(const float* __restrict__ wv, float* __restrict__ S) {
  __shared__ float p[256];
  const int t = threadIdx.x;
  float tot[RR];
  for (int r = 0; r < RR; ++r) {
    float s = 0.f;
    for (int n = t; n < NN; n += 256) s += wv[(size_t)r * NN + n];
    p[t] = s;
    __syncthreads();
    for (int off = 128; off > 0; off >>= 1) {
      if (t < off) p[t] += p[t + off];
      __syncthreads();
    }
    tot[r] = p[0];
    __syncthreads();
  }
  if (t == 0) {
    S[0] = tot[0]; S[1] = tot[1]; S[2] = tot[2];
    float w0 = tot[0] / (float)NN, w1 = tot[1] / (float)NN, w2 = tot[2] / (float)NN;
    float mx = fmaxf(w0, fmaxf(w1, w2));
    float e0 = __expf(w0 - mx), e1 = __expf(w1 - mx), e2 = __expf(w2 - mx);
    float inv = 1.f / (e0 + e1 + e2);
    S[4] = e0 * inv; S[5] = e1 * inv; S[6] = e2 * inv;
  }
}

__global__ void combine_f32(const float* __restrict__ z,
                            const float* __restrict__ S,
                            float* __restrict__ out) {
  const int idx = blockIdx.x * blockDim.x + threadIdx.x;
  if (idx >= NN * FD) return;
  out[idx] = S[4] * z[idx] + S[5] * z[(size_t)NN * FD + idx] +
             S[6] * z[2 * (size_t)NN * FD + idx];
}

// ------------------- fallback kernels (R10 CSR path, proven) ----------------
__global__ void gemm_el_er(const float* __restrict__ hin,
                           const float* __restrict__ W,
                           const float* __restrict__ al,
                           const float* __restrict__ ar,
                           float* __restrict__ f,
                           float* __restrict__ el,
                           float* __restrict__ er) {
  const int B8 = 8;
  __shared__ float lh[B8 * FD];
  const int j = threadIdx.x;
  const int n0 = blockIdx.x * B8;
#pragma unroll
  for (int i = 0; i < B8; ++i)
    lh[i * FD + j] = hin[(size_t)(n0 + i) * FD + j];
  __syncthreads();
  float acc[B8];
#pragma unroll
  for (int i = 0; i < B8; ++i) acc[i] = 0.f;
  for (int k = 0; k < FD; ++k) {
    const float w = W[(size_t)k * FD + j];
#pragma unroll
    for (int i = 0; i < B8; ++i) acc[i] += lh[i * FD + k] * w;
  }
  const float alv = al[j];
  const float arv = ar[j];
#pragma unroll
  for (int i = 0; i < B8; ++i) f[(size_t)(n0 + i) * FD + j] = acc[i];
  __syncthreads();
#pragma unroll
  for (int i = 0; i < B8; ++i) lh[i * FD + j] = acc[i] * alv;
  __syncthreads();
  if (j < B8 * 2) {
    const int i = j >> 1, h = j & 1;
    const float* p = &lh[i * FD + h * 64];
    float s = 0.f;
    for (int d = 0; d < 64; ++d) s += p[d];
    el[(size_t)(n0 + i) * 2 + h] = s;
  }
  __syncthreads();
#pragma unroll
  for (int i = 0; i < B8; ++i) lh[i * FD + j] = acc[i] * arv;
  __syncthreads();
  if (j < B8 * 2) {
    const int i = j >> 1, h = j & 1;
    const float* p = &lh[i * FD + h * 64];
    float s = 0.f;
    for (int d = 0; d < 64; ++d) s += p[d];
    er[(size_t)(n0 + i) * 2 + h] = s;
  }
}

__global__ void pull_aggr(const int* __restrict__ starts,
                          const int* __restrict__ csrsrc,
                          const float* __restrict__ el,
                          const float* __restrict__ er,
                          const float* __restrict__ f,
                          const float* __restrict__ b,
                          int do_relu,
                          float* __restrict__ z) {
  const int n = blockIdx.x;
  const int j = threadIdx.x;
  const int h = j >> 6;
  const int s0 = starts[n], s1 = starts[n + 1];
  const float ern = er[(size_t)n * 2 + h];
  float acc = 0.f, den = 0.f;
  for (int p = s0; p < s1; ++p) {
    const int src = csrsrc[p];
    const float w = leaky_exp(el[(size_t)src * 2 + h] + ern);
    den += w;
    acc += w * f[(size_t)src * FD + j];
  }
  float v = acc / fmaxf(den, 1e-9f) + b[j];
  if (do_relu) v = fmaxf(v, 0.f);
  z[(size_t)n * FD + j] = v;
}

__global__ void semw_nodes(const float* __restrict__ z,
                           const float* __restrict__ aw1,
                           const float* __restrict__ ab1,
                           const float* __restrict__ aw2,
                           float* __restrict__ wv) {
  __shared__ float lz[2][FD];
  __shared__ float red[2][4][AH];
  __shared__ float wcol[2][AH];
  const int g = threadIdx.x >> 7;
  const int t = threadIdx.x & 127;
  const int pair = blockIdx.x * 2 + g;
  const int n = pair / RR;
  const int r = pair - n * RR;
  lz[g][t] = z[((size_t)r * NN + n) * FD + t];
  __syncthreads();
  const int col = t & 31;
  const int part = t >> 5;
  float acc = 0.f;
#pragma unroll
  for (int kk = 0; kk < 32; ++kk) {
    const int k = part * 32 + kk;
    acc += lz[g][k] * aw1[(size_t)k * AH + col];
  }
  red[g][part][col] = acc;
  __syncthreads();
  if (part == 0) {
    float s = red[g][0][col] + red[g][1][col] + red[g][2][col] + red[g][3][col];
    wcol[g][col] = tanhf(s + ab1[col]) * aw2[col];
  }
  __syncthreads();
  if (t == 0) {
    float w = 0.f;
#pragma unroll
    for (int c = 0; c < AH; ++c) w += wcol[g][c];
    wv[(size_t)r * NN + n] = w;
  }
}

// ---------------------------------------------------------------------------
extern "C" void kernel_launch(void* const* d_in, const int* in_sizes, int n_in,
                              void* d_out, int out_size, void* d_ws, size_t ws_size,
                              hipStream_t stream) {
  const float* x   = (const float*)d_in[0];
  const int*   edg = (const int*)d_in[1];
  const float* W1  = (const float*)d_in[2];
  const float* al1 = (const float*)d_in[3];
  const float* ar1 = (const float*)d_in[4];
  const float* b1  = (const float*)d_in[5];
  const float* W2  = (const float*)d_in[6];
  const float* al2 = (const float*)d_in[7];
  const float* ar2 = (const float*)d_in[8];
  const float* b2  = (const float*)d_in[9];
  const float* aw1 = (const float*)d_in[10];
  const float* ab1 = (const float*)d_in[11];
  const float* aw2 = (const float*)d_in[12];
  const float* bw1 = (const float*)d_in[13];
  const float* bb1 = (const float*)d_in[14];
  const float* bw2 = (const float*)d_in[15];
  float* out = (float*)d_out;

  const size_t need_big = 67200128;  // gate proven on this ws
  if (ws_size >= need_big) {
    float* S      = (float*)d_ws;                    // 16
    float* wv     = S + 16;                          // RR*NN
    float* el     = wv + (size_t)RR * NN;            // RR*NN*2
    float* er     = el + (size_t)RR * NN * 2;        // RR*NN*2
    float* z      = er + (size_t)RR * NN * 2;        // RR*NN*FD fp32
    unsigned short* fb = (unsigned short*)(z + (size_t)RR * NN * FD);  // bf16
    int*   cnt    = (int*)(fb + (size_t)RR * NN * FD);  // RR*NN
    int*   starts = cnt + RR * NN;                   // RR*NP1
    int*   cursor = starts + RR * NP1;               // RR*NP1
    int*   csrsrc = cursor + RR * NP1;               // RR*EE

    hipMemsetAsync(cnt, 0, (size_t)RR * NN * sizeof(int), stream);
    csr_count<<<(RR * EE + 255) / 256, 256, 0, stream>>>(edg, cnt);
    csr_scan<<<RR, 256, 0, stream>>>(cnt, starts, cursor);
    csr_scatter<<<(RR * EE + 255) / 256, 256, 0, stream>>>(edg, cursor, csrsrc);

    // layer 1
    gemm_all<<<RR * (NN / BN), 64, 0, stream>>>(x, W1, al1, ar1, fb, el, er);
    pull_fused<<<RR * (NN / NPB), 256, 0, stream>>>(starts, csrsrc, el, er, fb,
                                                    b1, 1, aw1, ab1, aw2, z, wv);
    reduce_beta<<<1, 256, 0, stream>>>(wv, S);
    combine_f32<<<(NN * FD + 255) / 256, 256, 0, stream>>>(z, S, out);  // hmid

    // layer 2
    gemm_all<<<RR * (NN / BN), 64, 0, stream>>>(out, W2, al2, ar2, fb, el, er);
    pull_fused<<<RR * (NN / NPB), 256, 0, stream>>>(starts, csrsrc, el, er, fb,
                                                    b2, 0, bw1, bb1, bw2, z, wv);
    reduce_beta<<<1, 256, 0, stream>>>(wv, S);
    combine_f32<<<(NN * FD + 255) / 256, 256, 0, stream>>>(z, S, out);
    return;
  }

  // ---------------- fallback: R10 CSR path (46 MB, proven) ----------------
  float* S      = (float*)d_ws;
  float* wv     = S + 16;
  float* el     = wv + (size_t)RR * NN;
  float* er     = el + (size_t)NN * 2;
  float* f      = er + (size_t)NN * 2;
  float* z      = f + (size_t)NN * FD;
  int*   cnt    = (int*)(z + (size_t)RR * NN * FD);
  int*   starts = cnt + RR * NN;
  int*   cursor = starts + RR * NP1;
  int*   csrsrc = cursor + RR * NP1;

  hipMemsetAsync(cnt, 0, (size_t)RR * NN * sizeof(int), stream);
  csr_count<<<(RR * EE + 255) / 256, 256, 0, stream>>>(edg, cnt);
  csr_scan<<<RR, 256, 0, stream>>>(cnt, starts, cursor);
  csr_scatter<<<(RR * EE + 255) / 256, 256, 0, stream>>>(edg, cursor, csrsrc);

  for (int r = 0; r < RR; ++r) {
    gemm_el_er<<<NN / 8, 128, 0, stream>>>(
        x, W1 + (size_t)r * FD * FD, al1 + r * FD, ar1 + r * FD, f, el, er);
    pull_aggr<<<NN, 128, 0, stream>>>(starts + r * NP1, csrsrc + (size_t)r * EE,
                                      el, er, f, b1 + r * FD, 1,
                                      z + (size_t)r * NN * FD);
  }
  semw_nodes<<<NN * RR / 2, 256, 0, stream>>>(z, aw1, ab1, aw2, wv);
  reduce_beta<<<1, 256, 0, stream>>>(wv, S);
  combine_f32<<<(NN * FD + 255) / 256, 256, 0, stream>>>(z, S, out);

  for (int r = 0; r < RR; ++r) {
    gemm_el_er<<<NN / 8, 128, 0, stream>>>(
        out, W2 + (size_t)r * FD * FD, al2 + r * FD, ar2 + r * FD, f, el, er);
    pull_aggr<<<NN, 128, 0, stream>>>(starts + r * NP1, csrsrc + (size_t)r * EE,
                                      el, er, f, b2 + r * FD, 0,
                                      z + (size_t)r * NN * FD);
  }
  semw_nodes<<<NN * RR / 2, 256, 0, stream>>>(z, bw1, bb1, bw2, wv);
  reduce_beta<<<1, 256, 0, stream>>>(wv, S);
  combine_f32<<<(NN * FD + 255) / 256, 256, 0, stream>>>(z, S, out);
}

// Round 9
// 520.792 us; speedup vs baseline: 1.3179x; 1.2130x over previous
//
#include <hip/hip_runtime.h>
#include <hip/hip_bf16.h>

// Established facts (R3-R23): d_in = setup_inputs() dict order; floats fp32;
// edges int32; output fp32 [20000,128]. Pull history: coalesced row-gather
// 1.5 TB/s (R15); divergent node-per-lane 2.5 TB/s (R20); R21 (631.7us
// total) fused MLP into pull -> pull 90us with 13.2M LDS bank conflicts
// (lz[32][128]: stride%32==0 -> 8-way on MLP reads), occ 62%.
// R22 kernel (lz pad + lb(256,6) + uint4 + bucket epilogue) KILLED the
// container twice in two rounds -- no counters, cause unknown. This round
// de-risks: keep lz[32][130] pad + 1-read/4-FMA MLP (the theory under test)
// + R19-proven bucket epilogue; REVERT to R21-proven lb(256,4) and scalar
// uint gathers. Occupancy lever deferred until this runs.
#define NN 20000
#define RR 3
#define EE 320000
#define FD 128
#define AH 32
#define NP1 (NN + 1)
#define NEG_SLOPE 0.2f
#define BKN 256         // logit buckets per relation
#define NW 4            // waves per block in pull_fused
#define NPW2 8          // nodes per wave
#define NPB (NW * NPW2) // 32 nodes per block
#define LZP (FD + 2)    // padded LDS row: stride 130 (bank-conflict-free)

__device__ __forceinline__ int clamp_idx(int v) {
  v = v < 0 ? 0 : v;
  return v < NN ? v : NN - 1;
}
// leaky_relu(e) == max(e, 0.2*e) for all e (0.2e > e when e < 0)
__device__ __forceinline__ float leaky_exp(float e) {
  return __expf(fmaxf(e, NEG_SLOPE * e));
}
__device__ __forceinline__ float bf2f(unsigned short u) {
  union { unsigned int i; float f; } c;
  c.i = ((unsigned int)u) << 16;
  return c.f;
}
// fp32 -> bf16 with round-to-nearest-even (values are finite, |v| ~ O(1))
__device__ __forceinline__ unsigned short f2bf(float v) {
  union { float f; unsigned int i; } c;
  c.f = v;
  const unsigned int u = c.i;
  return (unsigned short)((u + 0x7fffu + ((u >> 16) & 1u)) >> 16);
}

// ----------------------------- CSR build -----------------------------------
__global__ void csr_count(const int* __restrict__ edg, int* __restrict__ cnt) {
  const int idx = blockIdx.x * blockDim.x + threadIdx.x;
  if (idx >= RR * EE) return;
  const int r = idx / EE, k = idx - r * EE;
  const int dst = clamp_idx(edg[(size_t)r * 2 * EE + EE + k]);
  atomicAdd(&cnt[r * NN + dst], 1);
}

// parallel Hillis-Steele scan over 256 partials (proven R19)
__global__ void csr_scan(const int* __restrict__ cnt, int* __restrict__ starts,
                         int* __restrict__ cursor) {
  __shared__ int part[256];
  const int r = blockIdx.x, t = threadIdx.x;
  const int CH = (NN + 255) / 256;  // 79
  const int lo = t * CH, hi = min(lo + CH, NN);
  int s = 0;
  for (int i = lo; i < hi; ++i) s += cnt[r * NN + i];
  part[t] = s;
  __syncthreads();
  for (int off = 1; off < 256; off <<= 1) {
    const int x = part[t];
    const int y = (t >= off) ? part[t - off] : 0;
    __syncthreads();
    part[t] = x + y;
    __syncthreads();
  }
  int run = (t == 0) ? 0 : part[t - 1];
  for (int i = lo; i < hi; ++i) {
    starts[r * NP1 + i] = run;
    cursor[r * NP1 + i] = run;
    run += cnt[r * NN + i];
  }
  if (t == 255) starts[r * NP1 + NN] = run;
}

__global__ void csr_scatter(const int* __restrict__ edg, int* __restrict__ cursor,
                            int* __restrict__ csrsrc) {
  const int idx = blockIdx.x * blockDim.x + threadIdx.x;
  if (idx >= RR * EE) return;
  const int r = idx / EE, k = idx - r * EE;
  const int src = clamp_idx(edg[(size_t)r * 2 * EE + k]);
  const int dst = clamp_idx(edg[(size_t)r * 2 * EE + EE + k]);
  const int pos = atomicAdd(&cursor[r * NP1 + dst], 1);
  csrsrc[(size_t)r * EE + pos] = src;
}

// ---------------------------------------------------------------------------
// Merged gemm (proven): block = 1 wave, BN=16 nodes, thread j owns cols j
// (head 0) and j+64 (head 1). el/er via shfl. f stored bf16.
// ---------------------------------------------------------------------------
#define BN 16
__global__ void __launch_bounds__(64, 4) gemm_all(
    const float* __restrict__ hin,            // [N,128]
    const float* __restrict__ W,              // [3,128,128]
    const float* __restrict__ al,             // [3,128]
    const float* __restrict__ ar,             // [3,128]
    unsigned short* __restrict__ fb,          // [3,N,128] bf16
    float* __restrict__ el,                   // [3,N,2]
    float* __restrict__ er) {
  __shared__ float lh[BN * FD];  // 8 KB
  const int blocksPerRel = NN / BN;  // 1250
  const int r = blockIdx.x / blocksPerRel;
  const int n0 = (blockIdx.x % blocksPerRel) * BN;
  const int j = threadIdx.x;  // 0..63

  {
    const float4* s4 = (const float4*)&hin[(size_t)n0 * FD];
    float4* d4 = (float4*)lh;
#pragma unroll
    for (int t = 0; t < 8; ++t) d4[j + 64 * t] = s4[j + 64 * t];
  }
  __syncthreads();

  const float* Wr = W + (size_t)r * FD * FD;
  float acc0[BN], acc1[BN];
#pragma unroll
  for (int i = 0; i < BN; ++i) { acc0[i] = 0.f; acc1[i] = 0.f; }

  for (int k4 = 0; k4 < FD; k4 += 4) {
    const float wa0 = Wr[(size_t)(k4 + 0) * FD + j];
    const float wb0 = Wr[(size_t)(k4 + 0) * FD + j + 64];
    const float wa1 = Wr[(size_t)(k4 + 1) * FD + j];
    const float wb1 = Wr[(size_t)(k4 + 1) * FD + j + 64];
    const float wa2 = Wr[(size_t)(k4 + 2) * FD + j];
    const float wb2 = Wr[(size_t)(k4 + 2) * FD + j + 64];
    const float wa3 = Wr[(size_t)(k4 + 3) * FD + j];
    const float wb3 = Wr[(size_t)(k4 + 3) * FD + j + 64];
#pragma unroll
    for (int i = 0; i < BN; ++i) {
      const float4 h4 = *(const float4*)&lh[i * FD + k4];
      acc0[i] = fmaf(h4.x, wa0, fmaf(h4.y, wa1, fmaf(h4.z, wa2, fmaf(h4.w, wa3, acc0[i]))));
      acc1[i] = fmaf(h4.x, wb0, fmaf(h4.y, wb1, fmaf(h4.z, wb2, fmaf(h4.w, wb3, acc1[i]))));
    }
  }

  const float al0 = al[r * FD + j];
  const float al1v = al[r * FD + j + 64];
  const float ar0 = ar[r * FD + j];
  const float ar1v = ar[r * FD + j + 64];

#pragma unroll
  for (int i = 0; i < BN; ++i) {
    const size_t row = ((size_t)r * NN + n0 + i) * FD;
    fb[row + j] = f2bf(acc0[i]);
    fb[row + j + 64] = f2bf(acc1[i]);
    float e0 = acc0[i] * al0;
    float e1 = acc1[i] * al1v;
    float u0 = acc0[i] * ar0;
    float u1 = acc1[i] * ar1v;
#pragma unroll
    for (int off = 32; off > 0; off >>= 1) {
      e0 += __shfl_down(e0, off, 64);
      e1 += __shfl_down(e1, off, 64);
      u0 += __shfl_down(u0, off, 64);
      u1 += __shfl_down(u1, off, 64);
    }
    if (j == 0) {
      const size_t base = ((size_t)r * NN + n0 + i) * 2;
      el[base + 0] = e0;
      el[base + 1] = e1;
      er[base + 0] = u0;
      er[base + 1] = u1;
    }
  }
}

// ---------------------------------------------------------------------------
// pull_fused v2 (de-risked): block = 4 waves = 32 nodes of one relation.
// Lane l of wave w owns (node, head=(l>>3)&1, quad=l>>4); per edge: 8
// scalar uint gathers (R21-proven body), per-lane divergent. acc = 8 x
// float2. Accumulation k-ascending per column => bit-identical z. LDS lz
// padded to [32][130] -> MLP reads hit 8 distinct banks (R21's [32][128]
// cost 13.2M conflict cycles); float2 stores <=2-way (free). MLP: 1 LDS
// read + 4 FMA per k. Per-node logit -> 256-bucket atomics (R19-proven).
// lb(256,4) = R21-proven.
// ---------------------------------------------------------------------------
__global__ void __launch_bounds__(256, 4) pull_fused(
    const int* __restrict__ starts,   // [3,NP1]
    const int* __restrict__ csrsrc,   // [3,E]
    const float* __restrict__ el,     // [3,N,2]
    const float* __restrict__ er,
    const unsigned short* __restrict__ fb,  // [3,N,128] bf16
    const float* __restrict__ b,      // [3,128]
    int do_relu,
    const float* __restrict__ aw1,    // [128,32]
    const float* __restrict__ ab1,    // [32]
    const float* __restrict__ aw2,    // [32]
    float* __restrict__ z,            // [3,N,128]
    float* __restrict__ bucket) {     // [3,BKN]
  __shared__ float lz[NPB][LZP];  // 32 x 130 floats = 16.6 KB
  const int t = threadIdx.x;
  const int wave = t >> 6;
  const int l = t & 63;
  const int bpr = NN / NPB;  // 625
  const int r = blockIdx.x / bpr;
  const int nb = (blockIdx.x - r * bpr) * NPB;
  const int widx = wave * NPW2 + (l & 7);  // node index within block 0..31
  const int node = nb + widx;
  const int h = (l >> 3) & 1;
  const int q = l >> 4;                    // 0..3
  const int rn = r * NN + node;
  const int* st = starts + r * NP1;
  const int* cs = csrsrc + (size_t)r * EE;
  const float2* el2 = (const float2*)(el + (size_t)r * NN * 2);
  const unsigned int* fru = (const unsigned int*)(fb + (size_t)r * NN * FD);
  const int s0 = st[node];
  const int deg = st[node + 1] - s0;
  const float ern = er[(size_t)rn * 2 + h];

  float2 acc[8];
#pragma unroll
  for (int i = 0; i < 8; ++i) acc[i] = make_float2(0.f, 0.f);
  float den = 0.f;

  // max degree over the 8 nodes of this wave (node id depends only on l&7)
  int md = deg;
  md = max(md, __shfl_xor(md, 1, 64));
  md = max(md, __shfl_xor(md, 2, 64));
  md = max(md, __shfl_xor(md, 4, 64));

  for (int k = 0; k < md; ++k) {
    if (k < deg) {
      const int src = cs[s0 + k];
      const float2 e2 = el2[src];
      const float w = leaky_exp((h ? e2.y : e2.x) + ern);
      den += w;
      const unsigned int* frow = fru + (src << 6) + (h << 5) + (q << 3);
#pragma unroll
      for (int cp = 0; cp < 8; ++cp) {
        const unsigned int fv = frow[cp];
        acc[cp].x += w * bf2f((unsigned short)(fv & 0xffff));
        acc[cp].y += w * bf2f((unsigned short)(fv >> 16));
      }
    }
  }

  const float inv = 1.f / fmaxf(den, 1e-9f);
  const int cbase = h * 64 + q * 16;
  const float* bb = b + r * FD + cbase;
  float* zr = z + (size_t)rn * FD + cbase;
#pragma unroll
  for (int cp = 0; cp < 8; ++cp) {
    float vx = acc[cp].x * inv + bb[2 * cp];
    float vy = acc[cp].y * inv + bb[2 * cp + 1];
    if (do_relu) { vx = fmaxf(vx, 0.f); vy = fmaxf(vy, 0.f); }
    ((float2*)zr)[cp] = make_float2(vx, vy);
    lz[widx][cbase + 2 * cp] = vx;
    lz[widx][cbase + 2 * cp + 1] = vy;
  }
  __syncthreads();

  // ---- fused semantic-attention logit for the block's 32 nodes ----
  // 8 threads per node; thread i owns cols i, i+8, i+16, i+24.
  const int mnode = t >> 3;   // 0..31
  const int i = t & 7;
  float a0 = ab1[i], a1 = ab1[i + 8], a2 = ab1[i + 16], a3 = ab1[i + 24];
  const float* aw1i = aw1 + i;
  for (int k = 0; k < FD; ++k) {
    const float zv = lz[mnode][k];
    const float* a = aw1i + (size_t)k * AH;
    a0 = fmaf(zv, a[0], a0);
    a1 = fmaf(zv, a[8], a1);
    a2 = fmaf(zv, a[16], a2);
    a3 = fmaf(zv, a[24], a3);
  }
  float part = tanhf(a0) * aw2[i] + tanhf(a1) * aw2[i + 8] +
               tanhf(a2) * aw2[i + 16] + tanhf(a3) * aw2[i + 24];
  part += __shfl_down(part, 4, 64);
  part += __shfl_down(part, 2, 64);
  part += __shfl_down(part, 1, 64);
  if (i == 0)
    atomicAdd(&bucket[r * BKN + ((nb + mnode) & (BKN - 1))], part);
}

// grid-strided combine; reduces the 3*BKN logit buckets in-block and applies
// the beta softmax inline (R19-proven; replaces reduce_beta + combine_f32)
__global__ void combine_bk(const float* __restrict__ z,
                           const float* __restrict__ bk,  // [3,BKN]
                           float* __restrict__ out) {
  __shared__ float p[256];
  __shared__ float beta[3];
  const int t = threadIdx.x;
  float tot[RR];
#pragma unroll
  for (int r = 0; r < RR; ++r) {
    p[t] = bk[r * BKN + t];
    __syncthreads();
    for (int off = 128; off > 0; off >>= 1) {
      if (t < off) p[t] += p[t + off];
      __syncthreads();
    }
    tot[r] = p[0];
    __syncthreads();
  }
  if (t == 0) {
    const float w0 = tot[0] * (1.f / NN);
    const float w1 = tot[1] * (1.f / NN);
    const float w2 = tot[2] * (1.f / NN);
    const float mx = fmaxf(w0, fmaxf(w1, w2));
    const float e0 = __expf(w0 - mx), e1 = __expf(w1 - mx), e2 = __expf(w2 - mx);
    const float inv = 1.f / (e0 + e1 + e2);
    beta[0] = e0 * inv; beta[1] = e1 * inv; beta[2] = e2 * inv;
  }
  __syncthreads();
  const float b0 = beta[0], b1 = beta[1], b2 = beta[2];
  for (int idx = blockIdx.x * 256 + t; idx < NN * FD; idx += gridDim.x * 256)
    out[idx] = b0 * z[idx] + b1 * z[(size_t)NN * FD + idx] +
               b2 * z[2 * (size_t)NN * FD + idx];
}

// ------------------- fallback kernels (R10 CSR path, proven) ----------------
__global__ void reduce_beta(const float* __restrict__ wv, float* __restrict__ S) {
  __shared__ float p[256];
  const int t = threadIdx.x;
  float tot[RR];
  for (int r = 0; r < RR; ++r) {
    float s = 0.f;
    for (int n = t; n < NN; n += 256) s += wv[(size_t)r * NN + n];
    p[t] = s;
    __syncthreads();
    for (int off = 128; off > 0; off >>= 1) {
      if (t < off) p[t] += p[t + off];
      __syncthreads();
    }
    tot[r] = p[0];
    __syncthreads();
  }
  if (t == 0) {
    S[0] = tot[0]; S[1] = tot[1]; S[2] = tot[2];
    float w0 = tot[0] / (float)NN, w1 = tot[1] / (float)NN, w2 = tot[2] / (float)NN;
    float mx = fmaxf(w0, fmaxf(w1, w2));
    float e0 = __expf(w0 - mx), e1 = __expf(w1 - mx), e2 = __expf(w2 - mx);
    float inv = 1.f / (e0 + e1 + e2);
    S[4] = e0 * inv; S[5] = e1 * inv; S[6] = e2 * inv;
  }
}

__global__ void combine_f32(const float* __restrict__ z,
                            const float* __restrict__ S,
                            float* __restrict__ out) {
  const int idx = blockIdx.x * blockDim.x + threadIdx.x;
  if (idx >= NN * FD) return;
  out[idx] = S[4] * z[idx] + S[5] * z[(size_t)NN * FD + idx] +
             S[6] * z[2 * (size_t)NN * FD + idx];
}

__global__ void gemm_el_er(const float* __restrict__ hin,
                           const float* __restrict__ W,
                           const float* __restrict__ al,
                           const float* __restrict__ ar,
                           float* __restrict__ f,
                           float* __restrict__ el,
                           float* __restrict__ er) {
  const int B8 = 8;
  __shared__ float lh[B8 * FD];
  const int j = threadIdx.x;
  const int n0 = blockIdx.x * B8;
#pragma unroll
  for (int i = 0; i < B8; ++i)
    lh[i * FD + j] = hin[(size_t)(n0 + i) * FD + j];
  __syncthreads();
  float acc[B8];
#pragma unroll
  for (int i = 0; i < B8; ++i) acc[i] = 0.f;
  for (int k = 0; k < FD; ++k) {
    const float w = W[(size_t)k * FD + j];
#pragma unroll
    for (int i = 0; i < B8; ++i) acc[i] += lh[i * FD + k] * w;
  }
  const float alv = al[j];
  const float arv = ar[j];
#pragma unroll
  for (int i = 0; i < B8; ++i) f[(size_t)(n0 + i) * FD + j] = acc[i];
  __syncthreads();
#pragma unroll
  for (int i = 0; i < B8; ++i) lh[i * FD + j] = acc[i] * alv;
  __syncthreads();
  if (j < B8 * 2) {
    const int i = j >> 1, h = j & 1;
    const float* p = &lh[i * FD + h * 64];
    float s = 0.f;
    for (int d = 0; d < 64; ++d) s += p[d];
    el[(size_t)(n0 + i) * 2 + h] = s;
  }
  __syncthreads();
#pragma unroll
  for (int i = 0; i < B8; ++i) lh[i * FD + j] = acc[i] * arv;
  __syncthreads();
  if (j < B8 * 2) {
    const int i = j >> 1, h = j & 1;
    const float* p = &lh[i * FD + h * 64];
    float s = 0.f;
    for (int d = 0; d < 64; ++d) s += p[d];
    er[(size_t)(n0 + i) * 2 + h] = s;
  }
}

__global__ void pull_aggr(const int* __restrict__ starts,
                          const int* __restrict__ csrsrc,
                          const float* __restrict__ el,
                          const float* __restrict__ er,
                          const float* __restrict__ f,
                          const float* __restrict__ b,
                          int do_relu,
                          float* __restrict__ z) {
  const int n = blockIdx.x;
  const int j = threadIdx.x;
  const int h = j >> 6;
  const int s0 = starts[n], s1 = starts[n + 1];
  const float ern = er[(size_t)n * 2 + h];
  float acc = 0.f, den = 0.f;
  for (int p = s0; p < s1; ++p) {
    const int src = csrsrc[p];
    const float w = leaky_exp(el[(size_t)src * 2 + h] + ern);
    den += w;
    acc += w * f[(size_t)src * FD + j];
  }
  float v = acc / fmaxf(den, 1e-9f) + b[j];
  if (do_relu) v = fmaxf(v, 0.f);
  z[(size_t)n * FD + j] = v;
}

__global__ void semw_nodes(const float* __restrict__ z,
                           const float* __restrict__ aw1,
                           const float* __restrict__ ab1,
                           const float* __restrict__ aw2,
                           float* __restrict__ wv) {
  __shared__ float lz[2][FD];
  __shared__ float red[2][4][AH];
  __shared__ float wcol[2][AH];
  const int g = threadIdx.x >> 7;
  const int t = threadIdx.x & 127;
  const int pair = blockIdx.x * 2 + g;
  const int n = pair / RR;
  const int r = pair - n * RR;
  lz[g][t] = z[((size_t)r * NN + n) * FD + t];
  __syncthreads();
  const int col = t & 31;
  const int part = t >> 5;
  float acc = 0.f;
#pragma unroll
  for (int kk = 0; kk < 32; ++kk) {
    const int k = part * 32 + kk;
    acc += lz[g][k] * aw1[(size_t)k * AH + col];
  }
  red[g][part][col] = acc;
  __syncthreads();
  if (part == 0) {
    float s = red[g][0][col] + red[g][1][col] + red[g][2][col] + red[g][3][col];
    wcol[g][col] = tanhf(s + ab1[col]) * aw2[col];
  }
  __syncthreads();
  if (t == 0) {
    float w = 0.f;
#pragma unroll
    for (int c = 0; c < AH; ++c) w += wcol[g][c];
    wv[(size_t)r * NN + n] = w;
  }
}

// ---------------------------------------------------------------------------
extern "C" void kernel_launch(void* const* d_in, const int* in_sizes, int n_in,
                              void* d_out, int out_size, void* d_ws, size_t ws_size,
                              hipStream_t stream) {
  const float* x   = (const float*)d_in[0];
  const int*   edg = (const int*)d_in[1];
  const float* W1  = (const float*)d_in[2];
  const float* al1 = (const float*)d_in[3];
  const float* ar1 = (const float*)d_in[4];
  const float* b1  = (const float*)d_in[5];
  const float* W2  = (const float*)d_in[6];
  const float* al2 = (const float*)d_in[7];
  const float* ar2 = (const float*)d_in[8];
  const float* b2  = (const float*)d_in[9];
  const float* aw1 = (const float*)d_in[10];
  const float* ab1 = (const float*)d_in[11];
  const float* aw2 = (const float*)d_in[12];
  const float* bw1 = (const float*)d_in[13];
  const float* bb1 = (const float*)d_in[14];
  const float* bw2 = (const float*)d_in[15];
  float* out = (float*)d_out;

  const size_t need_big = 67200128;  // gate proven on this ws
  if (ws_size >= need_big) {
    // layout (~51.5 MB):
    float* bk1    = (float*)d_ws;                    // RR*BKN
    float* bk2    = bk1 + RR * BKN;                  // RR*BKN
    float* el     = bk2 + RR * BKN;                  // RR*NN*2
    float* er     = el + (size_t)RR * NN * 2;        // RR*NN*2
    float* z      = er + (size_t)RR * NN * 2;        // RR*NN*FD fp32
    unsigned short* fb = (unsigned short*)(z + (size_t)RR * NN * FD);  // bf16
    int*   cnt    = (int*)(fb + (size_t)RR * NN * FD);  // RR*NN
    int*   starts = cnt + RR * NN;                   // RR*NP1
    int*   cursor = starts + RR * NP1;               // RR*NP1
    int*   csrsrc = cursor + RR * NP1;               // RR*EE

    hipMemsetAsync(bk1, 0, (size_t)2 * RR * BKN * sizeof(float), stream);
    hipMemsetAsync(cnt, 0, (size_t)RR * NN * sizeof(int), stream);
    csr_count<<<(RR * EE + 255) / 256, 256, 0, stream>>>(edg, cnt);
    csr_scan<<<RR, 256, 0, stream>>>(cnt, starts, cursor);
    csr_scatter<<<(RR * EE + 255) / 256, 256, 0, stream>>>(edg, cursor, csrsrc);

    // layer 1
    gemm_all<<<RR * (NN / BN), 64, 0, stream>>>(x, W1, al1, ar1, fb, el, er);
    pull_fused<<<RR * (NN / NPB), 256, 0, stream>>>(starts, csrsrc, el, er, fb,
                                                    b1, 1, aw1, ab1, aw2, z, bk1);
    combine_bk<<<640, 256, 0, stream>>>(z, bk1, out);  // hmid

    // layer 2
    gemm_all<<<RR * (NN / BN), 64, 0, stream>>>(out, W2, al2, ar2, fb, el, er);
    pull_fused<<<RR * (NN / NPB), 256, 0, stream>>>(starts, csrsrc, el, er, fb,
                                                    b2, 0, bw1, bb1, bw2, z, bk2);
    combine_bk<<<640, 256, 0, stream>>>(z, bk2, out);
    return;
  }

  // ---------------- fallback: R10 CSR path (46 MB, proven) ----------------
  float* S      = (float*)d_ws;
  float* wv     = S + 16;
  float* el     = wv + (size_t)RR * NN;
  float* er     = el + (size_t)NN * 2;
  float* f      = er + (size_t)NN * 2;
  float* z      = f + (size_t)NN * FD;
  int*   cnt    = (int*)(z + (size_t)RR * NN * FD);
  int*   starts = cnt + RR * NN;
  int*   cursor = starts + RR * NP1;
  int*   csrsrc = cursor + RR * NP1;

  hipMemsetAsync(cnt, 0, (size_t)RR * NN * sizeof(int), stream);
  csr_count<<<(RR * EE + 255) / 256, 256, 0, stream>>>(edg, cnt);
  csr_scan<<<RR, 256, 0, stream>>>(cnt, starts, cursor);
  csr_scatter<<<(RR * EE + 255) / 256, 256, 0, stream>>>(edg, cursor, csrsrc);

  for (int r = 0; r < RR; ++r) {
    gemm_el_er<<<NN / 8, 128, 0, stream>>>(
        x, W1 + (size_t)r * FD * FD, al1 + r * FD, ar1 + r * FD, f, el, er);
    pull_aggr<<<NN, 128, 0, stream>>>(starts + r * NP1, csrsrc + (size_t)r * EE,
                                      el, er, f, b1 + r * FD, 1,
                                      z + (size_t)r * NN * FD);
  }
  semw_nodes<<<NN * RR / 2, 256, 0, stream>>>(z, aw1, ab1, aw2, wv);
  reduce_beta<<<1, 256, 0, stream>>>(wv, S);
  combine_f32<<<(NN * FD + 255) / 256, 256, 0, stream>>>(z, S, out);

  for (int r = 0; r < RR; ++r) {
    gemm_el_er<<<NN / 8, 128, 0, stream>>>(
        out, W2 + (size_t)r * FD * FD, al2 + r * FD, ar2 + r * FD, f, el, er);
    pull_aggr<<<NN, 128, 0, stream>>>(starts + r * NP1, csrsrc + (size_t)r * EE,
                                      el, er, f, b2 + r * FD, 0,
                                      z + (size_t)r * NN * FD);
  }
  semw_nodes<<<NN * RR / 2, 256, 0, stream>>>(z, bw1, bb1, bw2, wv);
  reduce_beta<<<1, 256, 0, stream>>>(wv, S);
  combine_f32<<<(NN * FD + 255) / 256, 256, 0, stream>>>(z, S, out);
}

// Round 10
// 512.166 us; speedup vs baseline: 1.3401x; 1.0168x over previous
//
#include <hip/hip_runtime.h>
#include <hip/hip_bf16.h>

// Established facts (R3-R24): d_in = setup_inputs() dict order; floats fp32;
// edges int32; output fp32 [20000,128]. R24 = 520.8us PASSED (pad fix:
// conflicts 13.2M->240K; bucket epilogue). Pull invariants: VALU cut -> flat
// (R17); occ up -> flat (R18); conflicts cut 55x -> flat (R24). Arithmetic:
// 10 divergent vmem instrs per wave-iter x 4.7K/CU x ~45cy TA cost = 211K
// cycles = the 88us -> pull is TA(L1 address-processing)-bound.
// This round (single variable): 8 scalar uint fb gathers -> 2 x uint4
// (16B-aligned; fb ws offset %16==0) -> vmem instrs/iter 10->4. R22's
// container deaths attributed to infra (R24 shares all other diffs, ran 2x).
#define NN 20000
#define RR 3
#define EE 320000
#define FD 128
#define AH 32
#define NP1 (NN + 1)
#define NEG_SLOPE 0.2f
#define BKN 256         // logit buckets per relation
#define NW 4            // waves per block in pull_fused
#define NPW2 8          // nodes per wave
#define NPB (NW * NPW2) // 32 nodes per block
#define LZP (FD + 2)    // padded LDS row: stride 130 (bank-conflict-free)

__device__ __forceinline__ int clamp_idx(int v) {
  v = v < 0 ? 0 : v;
  return v < NN ? v : NN - 1;
}
// leaky_relu(e) == max(e, 0.2*e) for all e (0.2e > e when e < 0)
__device__ __forceinline__ float leaky_exp(float e) {
  return __expf(fmaxf(e, NEG_SLOPE * e));
}
__device__ __forceinline__ float bf2f(unsigned short u) {
  union { unsigned int i; float f; } c;
  c.i = ((unsigned int)u) << 16;
  return c.f;
}
// fp32 -> bf16 with round-to-nearest-even (values are finite, |v| ~ O(1))
__device__ __forceinline__ unsigned short f2bf(float v) {
  union { float f; unsigned int i; } c;
  c.f = v;
  const unsigned int u = c.i;
  return (unsigned short)((u + 0x7fffu + ((u >> 16) & 1u)) >> 16);
}

// ----------------------------- CSR build -----------------------------------
__global__ void csr_count(const int* __restrict__ edg, int* __restrict__ cnt) {
  const int idx = blockIdx.x * blockDim.x + threadIdx.x;
  if (idx >= RR * EE) return;
  const int r = idx / EE, k = idx - r * EE;
  const int dst = clamp_idx(edg[(size_t)r * 2 * EE + EE + k]);
  atomicAdd(&cnt[r * NN + dst], 1);
}

// parallel Hillis-Steele scan over 256 partials (proven R19)
__global__ void csr_scan(const int* __restrict__ cnt, int* __restrict__ starts,
                         int* __restrict__ cursor) {
  __shared__ int part[256];
  const int r = blockIdx.x, t = threadIdx.x;
  const int CH = (NN + 255) / 256;  // 79
  const int lo = t * CH, hi = min(lo + CH, NN);
  int s = 0;
  for (int i = lo; i < hi; ++i) s += cnt[r * NN + i];
  part[t] = s;
  __syncthreads();
  for (int off = 1; off < 256; off <<= 1) {
    const int x = part[t];
    const int y = (t >= off) ? part[t - off] : 0;
    __syncthreads();
    part[t] = x + y;
    __syncthreads();
  }
  int run = (t == 0) ? 0 : part[t - 1];
  for (int i = lo; i < hi; ++i) {
    starts[r * NP1 + i] = run;
    cursor[r * NP1 + i] = run;
    run += cnt[r * NN + i];
  }
  if (t == 255) starts[r * NP1 + NN] = run;
}

__global__ void csr_scatter(const int* __restrict__ edg, int* __restrict__ cursor,
                            int* __restrict__ csrsrc) {
  const int idx = blockIdx.x * blockDim.x + threadIdx.x;
  if (idx >= RR * EE) return;
  const int r = idx / EE, k = idx - r * EE;
  const int src = clamp_idx(edg[(size_t)r * 2 * EE + k]);
  const int dst = clamp_idx(edg[(size_t)r * 2 * EE + EE + k]);
  const int pos = atomicAdd(&cursor[r * NP1 + dst], 1);
  csrsrc[(size_t)r * EE + pos] = src;
}

// ---------------------------------------------------------------------------
// Merged gemm (proven): block = 1 wave, BN=16 nodes, thread j owns cols j
// (head 0) and j+64 (head 1). el/er via shfl. f stored bf16.
// ---------------------------------------------------------------------------
#define BN 16
__global__ void __launch_bounds__(64, 4) gemm_all(
    const float* __restrict__ hin,            // [N,128]
    const float* __restrict__ W,              // [3,128,128]
    const float* __restrict__ al,             // [3,128]
    const float* __restrict__ ar,             // [3,128]
    unsigned short* __restrict__ fb,          // [3,N,128] bf16
    float* __restrict__ el,                   // [3,N,2]
    float* __restrict__ er) {
  __shared__ float lh[BN * FD];  // 8 KB
  const int blocksPerRel = NN / BN;  // 1250
  const int r = blockIdx.x / blocksPerRel;
  const int n0 = (blockIdx.x % blocksPerRel) * BN;
  const int j = threadIdx.x;  // 0..63

  {
    const float4* s4 = (const float4*)&hin[(size_t)n0 * FD];
    float4* d4 = (float4*)lh;
#pragma unroll
    for (int t = 0; t < 8; ++t) d4[j + 64 * t] = s4[j + 64 * t];
  }
  __syncthreads();

  const float* Wr = W + (size_t)r * FD * FD;
  float acc0[BN], acc1[BN];
#pragma unroll
  for (int i = 0; i < BN; ++i) { acc0[i] = 0.f; acc1[i] = 0.f; }

  for (int k4 = 0; k4 < FD; k4 += 4) {
    const float wa0 = Wr[(size_t)(k4 + 0) * FD + j];
    const float wb0 = Wr[(size_t)(k4 + 0) * FD + j + 64];
    const float wa1 = Wr[(size_t)(k4 + 1) * FD + j];
    const float wb1 = Wr[(size_t)(k4 + 1) * FD + j + 64];
    const float wa2 = Wr[(size_t)(k4 + 2) * FD + j];
    const float wb2 = Wr[(size_t)(k4 + 2) * FD + j + 64];
    const float wa3 = Wr[(size_t)(k4 + 3) * FD + j];
    const float wb3 = Wr[(size_t)(k4 + 3) * FD + j + 64];
#pragma unroll
    for (int i = 0; i < BN; ++i) {
      const float4 h4 = *(const float4*)&lh[i * FD + k4];
      acc0[i] = fmaf(h4.x, wa0, fmaf(h4.y, wa1, fmaf(h4.z, wa2, fmaf(h4.w, wa3, acc0[i]))));
      acc1[i] = fmaf(h4.x, wb0, fmaf(h4.y, wb1, fmaf(h4.z, wb2, fmaf(h4.w, wb3, acc1[i]))));
    }
  }

  const float al0 = al[r * FD + j];
  const float al1v = al[r * FD + j + 64];
  const float ar0 = ar[r * FD + j];
  const float ar1v = ar[r * FD + j + 64];

#pragma unroll
  for (int i = 0; i < BN; ++i) {
    const size_t row = ((size_t)r * NN + n0 + i) * FD;
    fb[row + j] = f2bf(acc0[i]);
    fb[row + j + 64] = f2bf(acc1[i]);
    float e0 = acc0[i] * al0;
    float e1 = acc1[i] * al1v;
    float u0 = acc0[i] * ar0;
    float u1 = acc1[i] * ar1v;
#pragma unroll
    for (int off = 32; off > 0; off >>= 1) {
      e0 += __shfl_down(e0, off, 64);
      e1 += __shfl_down(e1, off, 64);
      u0 += __shfl_down(u0, off, 64);
      u1 += __shfl_down(u1, off, 64);
    }
    if (j == 0) {
      const size_t base = ((size_t)r * NN + n0 + i) * 2;
      el[base + 0] = e0;
      el[base + 1] = e1;
      er[base + 0] = u0;
      er[base + 1] = u1;
    }
  }
}

// ---------------------------------------------------------------------------
// pull_fused v3: identical to R24 (520.8us, proven) except the fb gather is
// two uint4 loads instead of 8 scalar uints (single-variable change).
// Rationale: 10 divergent vmem instrs/wave-iter -> 4; pull is TA-bound.
// Block = 4 waves = 32 nodes; lane owns (node, head, quad); acc = 8 x
// float2; accumulation k-ascending per column => bit-identical z.
// lz[32][130] pad (conflicts 240K, proven); bucket-atomic logits (proven).
// ---------------------------------------------------------------------------
__global__ void __launch_bounds__(256, 4) pull_fused(
    const int* __restrict__ starts,   // [3,NP1]
    const int* __restrict__ csrsrc,   // [3,E]
    const float* __restrict__ el,     // [3,N,2]
    const float* __restrict__ er,
    const unsigned short* __restrict__ fb,  // [3,N,128] bf16
    const float* __restrict__ b,      // [3,128]
    int do_relu,
    const float* __restrict__ aw1,    // [128,32]
    const float* __restrict__ ab1,    // [32]
    const float* __restrict__ aw2,    // [32]
    float* __restrict__ z,            // [3,N,128]
    float* __restrict__ bucket) {     // [3,BKN]
  __shared__ float lz[NPB][LZP];  // 32 x 130 floats = 16.6 KB
  const int t = threadIdx.x;
  const int wave = t >> 6;
  const int l = t & 63;
  const int bpr = NN / NPB;  // 625
  const int r = blockIdx.x / bpr;
  const int nb = (blockIdx.x - r * bpr) * NPB;
  const int widx = wave * NPW2 + (l & 7);  // node index within block 0..31
  const int node = nb + widx;
  const int h = (l >> 3) & 1;
  const int q = l >> 4;                    // 0..3
  const int rn = r * NN + node;
  const int* st = starts + r * NP1;
  const int* cs = csrsrc + (size_t)r * EE;
  const float2* el2 = (const float2*)(el + (size_t)r * NN * 2);
  const unsigned int* fru = (const unsigned int*)(fb + (size_t)r * NN * FD);
  const int s0 = st[node];
  const int deg = st[node + 1] - s0;
  const float ern = er[(size_t)rn * 2 + h];

  float2 acc[8];
#pragma unroll
  for (int i = 0; i < 8; ++i) acc[i] = make_float2(0.f, 0.f);
  float den = 0.f;

  // max degree over the 8 nodes of this wave (node id depends only on l&7)
  int md = deg;
  md = max(md, __shfl_xor(md, 1, 64));
  md = max(md, __shfl_xor(md, 2, 64));
  md = max(md, __shfl_xor(md, 4, 64));

  for (int k = 0; k < md; ++k) {
    if (k < deg) {
      const int src = cs[s0 + k];
      const float2 e2 = el2[src];
      const float w = leaky_exp((h ? e2.y : e2.x) + ern);
      den += w;
      const uint4* frow = (const uint4*)(fru + (src << 6) + (h << 5) + (q << 3));
      const uint4 fa = frow[0];
      const uint4 fbv = frow[1];
      acc[0].x += w * bf2f((unsigned short)(fa.x & 0xffff));
      acc[0].y += w * bf2f((unsigned short)(fa.x >> 16));
      acc[1].x += w * bf2f((unsigned short)(fa.y & 0xffff));
      acc[1].y += w * bf2f((unsigned short)(fa.y >> 16));
      acc[2].x += w * bf2f((unsigned short)(fa.z & 0xffff));
      acc[2].y += w * bf2f((unsigned short)(fa.z >> 16));
      acc[3].x += w * bf2f((unsigned short)(fa.w & 0xffff));
      acc[3].y += w * bf2f((unsigned short)(fa.w >> 16));
      acc[4].x += w * bf2f((unsigned short)(fbv.x & 0xffff));
      acc[4].y += w * bf2f((unsigned short)(fbv.x >> 16));
      acc[5].x += w * bf2f((unsigned short)(fbv.y & 0xffff));
      acc[5].y += w * bf2f((unsigned short)(fbv.y >> 16));
      acc[6].x += w * bf2f((unsigned short)(fbv.z & 0xffff));
      acc[6].y += w * bf2f((unsigned short)(fbv.z >> 16));
      acc[7].x += w * bf2f((unsigned short)(fbv.w & 0xffff));
      acc[7].y += w * bf2f((unsigned short)(fbv.w >> 16));
    }
  }

  const float inv = 1.f / fmaxf(den, 1e-9f);
  const int cbase = h * 64 + q * 16;
  const float* bb = b + r * FD + cbase;
  float* zr = z + (size_t)rn * FD + cbase;
#pragma unroll
  for (int cp = 0; cp < 8; ++cp) {
    float vx = acc[cp].x * inv + bb[2 * cp];
    float vy = acc[cp].y * inv + bb[2 * cp + 1];
    if (do_relu) { vx = fmaxf(vx, 0.f); vy = fmaxf(vy, 0.f); }
    ((float2*)zr)[cp] = make_float2(vx, vy);
    lz[widx][cbase + 2 * cp] = vx;
    lz[widx][cbase + 2 * cp + 1] = vy;
  }
  __syncthreads();

  // ---- fused semantic-attention logit for the block's 32 nodes ----
  // 8 threads per node; thread i owns cols i, i+8, i+16, i+24.
  const int mnode = t >> 3;   // 0..31
  const int i = t & 7;
  float a0 = ab1[i], a1 = ab1[i + 8], a2 = ab1[i + 16], a3 = ab1[i + 24];
  const float* aw1i = aw1 + i;
  for (int k = 0; k < FD; ++k) {
    const float zv = lz[mnode][k];
    const float* a = aw1i + (size_t)k * AH;
    a0 = fmaf(zv, a[0], a0);
    a1 = fmaf(zv, a[8], a1);
    a2 = fmaf(zv, a[16], a2);
    a3 = fmaf(zv, a[24], a3);
  }
  float part = tanhf(a0) * aw2[i] + tanhf(a1) * aw2[i + 8] +
               tanhf(a2) * aw2[i + 16] + tanhf(a3) * aw2[i + 24];
  part += __shfl_down(part, 4, 64);
  part += __shfl_down(part, 2, 64);
  part += __shfl_down(part, 1, 64);
  if (i == 0)
    atomicAdd(&bucket[r * BKN + ((nb + mnode) & (BKN - 1))], part);
}

// grid-strided combine; reduces the 3*BKN logit buckets in-block and applies
// the beta softmax inline (R19/R24-proven)
__global__ void combine_bk(const float* __restrict__ z,
                           const float* __restrict__ bk,  // [3,BKN]
                           float* __restrict__ out) {
  __shared__ float p[256];
  __shared__ float beta[3];
  const int t = threadIdx.x;
  float tot[RR];
#pragma unroll
  for (int r = 0; r < RR; ++r) {
    p[t] = bk[r * BKN + t];
    __syncthreads();
    for (int off = 128; off > 0; off >>= 1) {
      if (t < off) p[t] += p[t + off];
      __syncthreads();
    }
    tot[r] = p[0];
    __syncthreads();
  }
  if (t == 0) {
    const float w0 = tot[0] * (1.f / NN);
    const float w1 = tot[1] * (1.f / NN);
    const float w2 = tot[2] * (1.f / NN);
    const float mx = fmaxf(w0, fmaxf(w1, w2));
    const float e0 = __expf(w0 - mx), e1 = __expf(w1 - mx), e2 = __expf(w2 - mx);
    const float inv = 1.f / (e0 + e1 + e2);
    beta[0] = e0 * inv; beta[1] = e1 * inv; beta[2] = e2 * inv;
  }
  __syncthreads();
  const float b0 = beta[0], b1 = beta[1], b2 = beta[2];
  for (int idx = blockIdx.x * 256 + t; idx < NN * FD; idx += gridDim.x * 256)
    out[idx] = b0 * z[idx] + b1 * z[(size_t)NN * FD + idx] +
               b2 * z[2 * (size_t)NN * FD + idx];
}

// ------------------- fallback kernels (R10 CSR path, proven) ----------------
__global__ void reduce_beta(const float* __restrict__ wv, float* __restrict__ S) {
  __shared__ float p[256];
  const int t = threadIdx.x;
  float tot[RR];
  for (int r = 0; r < RR; ++r) {
    float s = 0.f;
    for (int n = t; n < NN; n += 256) s += wv[(size_t)r * NN + n];
    p[t] = s;
    __syncthreads();
    for (int off = 128; off > 0; off >>= 1) {
      if (t < off) p[t] += p[t + off];
      __syncthreads();
    }
    tot[r] = p[0];
    __syncthreads();
  }
  if (t == 0) {
    S[0] = tot[0]; S[1] = tot[1]; S[2] = tot[2];
    float w0 = tot[0] / (float)NN, w1 = tot[1] / (float)NN, w2 = tot[2] / (float)NN;
    float mx = fmaxf(w0, fmaxf(w1, w2));
    float e0 = __expf(w0 - mx), e1 = __expf(w1 - mx), e2 = __expf(w2 - mx);
    float inv = 1.f / (e0 + e1 + e2);
    S[4] = e0 * inv; S[5] = e1 * inv; S[6] = e2 * inv;
  }
}

__global__ void combine_f32(const float* __restrict__ z,
                            const float* __restrict__ S,
                            float* __restrict__ out) {
  const int idx = blockIdx.x * blockDim.x + threadIdx.x;
  if (idx >= NN * FD) return;
  out[idx] = S[4] * z[idx] + S[5] * z[(size_t)NN * FD + idx] +
             S[6] * z[2 * (size_t)NN * FD + idx];
}

__global__ void gemm_el_er(const float* __restrict__ hin,
                           const float* __restrict__ W,
                           const float* __restrict__ al,
                           const float* __restrict__ ar,
                           float* __restrict__ f,
                           float* __restrict__ el,
                           float* __restrict__ er) {
  const int B8 = 8;
  __shared__ float lh[B8 * FD];
  const int j = threadIdx.x;
  const int n0 = blockIdx.x * B8;
#pragma unroll
  for (int i = 0; i < B8; ++i)
    lh[i * FD + j] = hin[(size_t)(n0 + i) * FD + j];
  __syncthreads();
  float acc[B8];
#pragma unroll
  for (int i = 0; i < B8; ++i) acc[i] = 0.f;
  for (int k = 0; k < FD; ++k) {
    const float w = W[(size_t)k * FD + j];
#pragma unroll
    for (int i = 0; i < B8; ++i) acc[i] += lh[i * FD + k] * w;
  }
  const float alv = al[j];
  const float arv = ar[j];
#pragma unroll
  for (int i = 0; i < B8; ++i) f[(size_t)(n0 + i) * FD + j] = acc[i];
  __syncthreads();
#pragma unroll
  for (int i = 0; i < B8; ++i) lh[i * FD + j] = acc[i] * alv;
  __syncthreads();
  if (j < B8 * 2) {
    const int i = j >> 1, h = j & 1;
    const float* p = &lh[i * FD + h * 64];
    float s = 0.f;
    for (int d = 0; d < 64; ++d) s += p[d];
    el[(size_t)(n0 + i) * 2 + h] = s;
  }
  __syncthreads();
#pragma unroll
  for (int i = 0; i < B8; ++i) lh[i * FD + j] = acc[i] * arv;
  __syncthreads();
  if (j < B8 * 2) {
    const int i = j >> 1, h = j & 1;
    const float* p = &lh[i * FD + h * 64];
    float s = 0.f;
    for (int d = 0; d < 64; ++d) s += p[d];
    er[(size_t)(n0 + i) * 2 + h] = s;
  }
}

__global__ void pull_aggr(const int* __restrict__ starts,
                          const int* __restrict__ csrsrc,
                          const float* __restrict__ el,
                          const float* __restrict__ er,
                          const float* __restrict__ f,
                          const float* __restrict__ b,
                          int do_relu,
                          float* __restrict__ z) {
  const int n = blockIdx.x;
  const int j = threadIdx.x;
  const int h = j >> 6;
  const int s0 = starts[n], s1 = starts[n + 1];
  const float ern = er[(size_t)n * 2 + h];
  float acc = 0.f, den = 0.f;
  for (int p = s0; p < s1; ++p) {
    const int src = csrsrc[p];
    const float w = leaky_exp(el[(size_t)src * 2 + h] + ern);
    den += w;
    acc += w * f[(size_t)src * FD + j];
  }
  float v = acc / fmaxf(den, 1e-9f) + b[j];
  if (do_relu) v = fmaxf(v, 0.f);
  z[(size_t)n * FD + j] = v;
}

__global__ void semw_nodes(const float* __restrict__ z,
                           const float* __restrict__ aw1,
                           const float* __restrict__ ab1,
                           const float* __restrict__ aw2,
                           float* __restrict__ wv) {
  __shared__ float lz[2][FD];
  __shared__ float red[2][4][AH];
  __shared__ float wcol[2][AH];
  const int g = threadIdx.x >> 7;
  const int t = threadIdx.x & 127;
  const int pair = blockIdx.x * 2 + g;
  const int n = pair / RR;
  const int r = pair - n * RR;
  lz[g][t] = z[((size_t)r * NN + n) * FD + t];
  __syncthreads();
  const int col = t & 31;
  const int part = t >> 5;
  float acc = 0.f;
#pragma unroll
  for (int kk = 0; kk < 32; ++kk) {
    const int k = part * 32 + kk;
    acc += lz[g][k] * aw1[(size_t)k * AH + col];
  }
  red[g][part][col] = acc;
  __syncthreads();
  if (part == 0) {
    float s = red[g][0][col] + red[g][1][col] + red[g][2][col] + red[g][3][col];
    wcol[g][col] = tanhf(s + ab1[col]) * aw2[col];
  }
  __syncthreads();
  if (t == 0) {
    float w = 0.f;
#pragma unroll
    for (int c = 0; c < AH; ++c) w += wcol[g][c];
    wv[(size_t)r * NN + n] = w;
  }
}

// ---------------------------------------------------------------------------
extern "C" void kernel_launch(void* const* d_in, const int* in_sizes, int n_in,
                              void* d_out, int out_size, void* d_ws, size_t ws_size,
                              hipStream_t stream) {
  const float* x   = (const float*)d_in[0];
  const int*   edg = (const int*)d_in[1];
  const float* W1  = (const float*)d_in[2];
  const float* al1 = (const float*)d_in[3];
  const float* ar1 = (const float*)d_in[4];
  const float* b1  = (const float*)d_in[5];
  const float* W2  = (const float*)d_in[6];
  const float* al2 = (const float*)d_in[7];
  const float* ar2 = (const float*)d_in[8];
  const float* b2  = (const float*)d_in[9];
  const float* aw1 = (const float*)d_in[10];
  const float* ab1 = (const float*)d_in[11];
  const float* aw2 = (const float*)d_in[12];
  const float* bw1 = (const float*)d_in[13];
  const float* bb1 = (const float*)d_in[14];
  const float* bw2 = (const float*)d_in[15];
  float* out = (float*)d_out;

  const size_t need_big = 67200128;  // gate proven on this ws
  if (ws_size >= need_big) {
    // layout (~51.5 MB):
    float* bk1    = (float*)d_ws;                    // RR*BKN
    float* bk2    = bk1 + RR * BKN;                  // RR*BKN
    float* el     = bk2 + RR * BKN;                  // RR*NN*2
    float* er     = el + (size_t)RR * NN * 2;        // RR*NN*2
    float* z      = er + (size_t)RR * NN * 2;        // RR*NN*FD fp32
    unsigned short* fb = (unsigned short*)(z + (size_t)RR * NN * FD);  // bf16
    int*   cnt    = (int*)(fb + (size_t)RR * NN * FD);  // RR*NN
    int*   starts = cnt + RR * NN;                   // RR*NP1
    int*   cursor = starts + RR * NP1;               // RR*NP1
    int*   csrsrc = cursor + RR * NP1;               // RR*EE

    hipMemsetAsync(bk1, 0, (size_t)2 * RR * BKN * sizeof(float), stream);
    hipMemsetAsync(cnt, 0, (size_t)RR * NN * sizeof(int), stream);
    csr_count<<<(RR * EE + 255) / 256, 256, 0, stream>>>(edg, cnt);
    csr_scan<<<RR, 256, 0, stream>>>(cnt, starts, cursor);
    csr_scatter<<<(RR * EE + 255) / 256, 256, 0, stream>>>(edg, cursor, csrsrc);

    // layer 1
    gemm_all<<<RR * (NN / BN), 64, 0, stream>>>(x, W1, al1, ar1, fb, el, er);
    pull_fused<<<RR * (NN / NPB), 256, 0, stream>>>(starts, csrsrc, el, er, fb,
                                                    b1, 1, aw1, ab1, aw2, z, bk1);
    combine_bk<<<640, 256, 0, stream>>>(z, bk1, out);  // hmid

    // layer 2
    gemm_all<<<RR * (NN / BN), 64, 0, stream>>>(out, W2, al2, ar2, fb, el, er);
    pull_fused<<<RR * (NN / NPB), 256, 0, stream>>>(starts, csrsrc, el, er, fb,
                                                    b2, 0, bw1, bb1, bw2, z, bk2);
    combine_bk<<<640, 256, 0, stream>>>(z, bk2, out);
    return;
  }

  // ---------------- fallback: R10 CSR path (46 MB, proven) ----------------
  float* S      = (float*)d_ws;
  float* wv     = S + 16;
  float* el     = wv + (size_t)RR * NN;
  float* er     = el + (size_t)NN * 2;
  float* f      = er + (size_t)NN * 2;
  float* z      = f + (size_t)NN * FD;
  int*   cnt    = (int*)(z + (size_t)RR * NN * FD);
  int*   starts = cnt + RR * NN;
  int*   cursor = starts + RR * NP1;
  int*   csrsrc = cursor + RR * NP1;

  hipMemsetAsync(cnt, 0, (size_t)RR * NN * sizeof(int), stream);
  csr_count<<<(RR * EE + 255) / 256, 256, 0, stream>>>(edg, cnt);
  csr_scan<<<RR, 256, 0, stream>>>(cnt, starts, cursor);
  csr_scatter<<<(RR * EE + 255) / 256, 256, 0, stream>>>(edg, cursor, csrsrc);

  for (int r = 0; r < RR; ++r) {
    gemm_el_er<<<NN / 8, 128, 0, stream>>>(
        x, W1 + (size_t)r * FD * FD, al1 + r * FD, ar1 + r * FD, f, el, er);
    pull_aggr<<<NN, 128, 0, stream>>>(starts + r * NP1, csrsrc + (size_t)r * EE,
                                      el, er, f, b1 + r * FD, 1,
                                      z + (size_t)r * NN * FD);
  }
  semw_nodes<<<NN * RR / 2, 256, 0, stream>>>(z, aw1, ab1, aw2, wv);
  reduce_beta<<<1, 256, 0, stream>>>(wv, S);
  combine_f32<<<(NN * FD + 255) / 256, 256, 0, stream>>>(z, S, out);

  for (int r = 0; r < RR; ++r) {
    gemm_el_er<<<NN / 8, 128, 0, stream>>>(
        out, W2 + (size_t)r * FD * FD, al2 + r * FD, ar2 + r * FD, f, el, er);
    pull_aggr<<<NN, 128, 0, stream>>>(starts + r * NP1, csrsrc + (size_t)r * EE,
                                      el, er, f, b2 + r * FD, 0,
                                      z + (size_t)r * NN * FD);
  }
  semw_nodes<<<NN * RR / 2, 256, 0, stream>>>(z, bw1, bb1, bw2, wv);
  reduce_beta<<<1, 256, 0, stream>>>(wv, S);
  combine_f32<<<(NN * FD + 255) / 256, 256, 0, stream>>>(z, S, out);
}